// Round 14
// baseline (269.904 us; speedup 1.0000x reference)
//
#include <hip/hip_runtime.h>
#include <math.h>

#define NFEAT 128
#define EPSBN 1e-5f
#define NREP 8    // logit3 replicas to spread atomic contention
#define LDT 72    // k_gram transposed-tile row stride (shorts): 16B-aligned cols

typedef __attribute__((ext_vector_type(8))) short short8;
typedef __attribute__((ext_vector_type(4))) float f32x4;

__device__ __forceinline__ unsigned short f2bf(float x) {
  union { float f; unsigned u; } v; v.f = x;
  unsigned r = v.u + 0x7FFF + ((v.u >> 16) & 1);   // RNE
  return (unsigned short)(r >> 16);
}
__device__ __forceinline__ float bf2f(unsigned short h) {
  union { unsigned u; float f; } v; v.u = (unsigned)h << 16;
  return v.f;
}

// ---------------------------------------------------------------------------
// KP_fold: fold back-half into MT + cb.  grid=6.
//   logits = S@M1 + I@M3 + R@M4 + NB@M2 + cb
// MT layout: MT[cl*512 + part*128 + k], part: 0=S 1=I 2=R 3=NB.
// ---------------------------------------------------------------------------
__global__ __launch_bounds__(256) void kp_fold(
    const float* __restrict__ WtoI, const float* __restrict__ btoI,
    const float* __restrict__ WtoR, const float* __restrict__ btoR,
    const float* __restrict__ Wout, const float* __restrict__ bout,
    float* __restrict__ MT, float* __restrict__ cb)
{
  const int tid = threadIdx.x;
  int t = blockIdx.x * 256 + tid;     // 0..1535
  int cl = t / 512;
  int idx = t - cl * 512;
  int part = idx >> 7, k = idx & 127;
  float val;
  if (part == 0) {            // S: Wo1 + WtoI_top @ (Wo2-Wo1)
    float s = Wout[k * 3 + cl];
    for (int f = 0; f < 128; f++)
      s = fmaf(WtoI[k * 128 + f],
               Wout[(128 + f) * 3 + cl] - Wout[f * 3 + cl], s);
    val = s;
  } else if (part == 1) {     // I: Wo2 + WtoR @ (Wo3-Wo2)
    float s = Wout[(128 + k) * 3 + cl];
    for (int f = 0; f < 128; f++)
      s = fmaf(WtoR[k * 128 + f],
               Wout[(256 + f) * 3 + cl] - Wout[(128 + f) * 3 + cl], s);
    val = s;
  } else if (part == 2) {     // R: Wo3
    val = Wout[(256 + k) * 3 + cl];
  } else {                    // NB: WtoI_bot @ (Wo2-Wo1)
    float s = 0.f;
    for (int f = 0; f < 128; f++)
      s = fmaf(WtoI[(128 + k) * 128 + f],
               Wout[(128 + f) * 3 + cl] - Wout[f * 3 + cl], s);
    val = s;
  }
  MT[cl * 512 + idx] = val;

  if (blockIdx.x == 0 && tid < 3) {
    float s = bout[tid];
    for (int f = 0; f < 128; f++) {
      s = fmaf(btoI[f], Wout[(128 + f) * 3 + tid] - Wout[f * 3 + tid], s);
      s = fmaf(btoR[f], Wout[(256 + f) * 3 + tid] - Wout[(128 + f) * 3 + tid], s);
    }
    cb[tid] = s;
  }
}

// ---------------------------------------------------------------------------
// K_gram: Gpart[bid] = partial feat^T @ feat over this block's 64-row chunks
// (split-bf16: Ah^TAh + Al^TAh + Ah^TAl — symmetric), plus colsum s via
// ones-vector MFMA.  feat staged TRANSPOSED in LDS: T[col][row], LDT=72, so
// both MFMA operands are contiguous ds_read_b128.  Rows >= N zero-padded.
// ---------------------------------------------------------------------------
__global__ __launch_bounds__(512, 2) void k_gram(
    const float* __restrict__ feat,
    float* __restrict__ Gpart,   // gridDim.x * 16384
    float* __restrict__ sg,      // 128, pre-zeroed
    int N, int ntiles)
{
  __shared__ short Th[2][128 * LDT];   // 2 x 18 KB
  __shared__ short Tl[2][128 * LDT];

  const int tid  = threadIdx.x;
  const int lane = tid & 63;
  const int wv   = tid >> 6;
  const int kg   = lane >> 4;
  const int l15  = lane & 15;
  const int r    = tid >> 3;           // staging row 0..63
  const int o    = tid & 7;            // staging 16-col group

  const short one = (short)0x3F80;     // bf16 1.0
  const short8 ones = {one, one, one, one, one, one, one, one};

  f32x4 acc[8];
  f32x4 accs = (f32x4){0.f, 0.f, 0.f, 0.f};
#pragma unroll
  for (int t = 0; t < 8; t++) acc[t] = (f32x4){0.f, 0.f, 0.f, 0.f};

  float4 pf[4];
  // prologue: load chunk0 (rotated float4 order) and stage into buffer 0
  {
    int gr = blockIdx.x * 64 + r;
    if (gr < N) {
      const float4* s4 = (const float4*)(feat + (size_t)gr * NFEAT + o * 16);
#pragma unroll
      for (int qq = 0; qq < 4; qq++) pf[qq] = s4[(qq + r) & 3];
    } else {
#pragma unroll
      for (int qq = 0; qq < 4; qq++) pf[qq] = make_float4(0.f, 0.f, 0.f, 0.f);
    }
#pragma unroll
    for (int qq = 0; qq < 4; qq++) {
      float xv[4] = {pf[qq].x, pf[qq].y, pf[qq].z, pf[qq].w};
#pragma unroll
      for (int cc = 0; cc < 4; cc++) {
        int col = o * 16 + (((qq + r) & 3) << 2) + cc;
        unsigned short h = f2bf(xv[cc]);
        Th[0][col * LDT + r] = (short)h;
        Tl[0][col * LDT + r] = (short)f2bf(xv[cc] - bf2f(h));
      }
    }
  }
  __syncthreads();

  int cur = 0;
  for (int tile = blockIdx.x; tile < ntiles; tile += gridDim.x) {
    const int ntile = tile + gridDim.x;
    const bool have_next = ntile < ntiles;

    // issue next chunk's prefetch (in flight during MFMA)
    if (have_next) {
      int gr = ntile * 64 + r;
      if (gr < N) {
        const float4* s4 = (const float4*)(feat + (size_t)gr * NFEAT + o * 16);
#pragma unroll
        for (int qq = 0; qq < 4; qq++) pf[qq] = s4[(qq + r) & 3];
      } else {
#pragma unroll
        for (int qq = 0; qq < 4; qq++) pf[qq] = make_float4(0.f, 0.f, 0.f, 0.f);
      }
    }

    const short* th = &Th[cur][0];
    const short* tl = &Tl[cur][0];

#pragma unroll
    for (int kf = 0; kf < 2; kf++) {
      int abase = (wv * 16 + l15) * LDT + kf * 32 + kg * 8;
      short8 ah = *(const short8*)&th[abase];
      short8 al = *(const short8*)&tl[abase];
      accs = __builtin_amdgcn_mfma_f32_16x16x32_bf16(ones, ah, accs, 0, 0, 0);
      accs = __builtin_amdgcn_mfma_f32_16x16x32_bf16(ones, al, accs, 0, 0, 0);
#pragma unroll
      for (int t = 0; t < 8; t++) {
        int bbase = (t * 16 + l15) * LDT + kf * 32 + kg * 8;
        short8 bh = *(const short8*)&th[bbase];
        short8 bl = *(const short8*)&tl[bbase];
        acc[t] = __builtin_amdgcn_mfma_f32_16x16x32_bf16(ah, bh, acc[t], 0, 0, 0);
        acc[t] = __builtin_amdgcn_mfma_f32_16x16x32_bf16(al, bh, acc[t], 0, 0, 0);
        acc[t] = __builtin_amdgcn_mfma_f32_16x16x32_bf16(ah, bl, acc[t], 0, 0, 0);
      }
    }

    // convert prefetched regs into buf[cur^1]
    if (have_next) {
      int nb = cur ^ 1;
#pragma unroll
      for (int qq = 0; qq < 4; qq++) {
        float xv[4] = {pf[qq].x, pf[qq].y, pf[qq].z, pf[qq].w};
#pragma unroll
        for (int cc = 0; cc < 4; cc++) {
          int col = o * 16 + (((qq + r) & 3) << 2) + cc;
          unsigned short h = f2bf(xv[cc]);
          Th[nb][col * LDT + r] = (short)h;
          Tl[nb][col * LDT + r] = (short)f2bf(xv[cc] - bf2f(h));
        }
      }
    }
    __syncthreads();
    cur ^= 1;
  }

  // write partial G; accumulate s (all rows of accs identical; take kg==0,g=0)
  float* gp = Gpart + (size_t)blockIdx.x * 16384;
#pragma unroll
  for (int t = 0; t < 8; t++)
#pragma unroll
    for (int g = 0; g < 4; g++) {
      int row = wv * 16 + kg * 4 + g;
      gp[row * 128 + t * 16 + l15] = acc[t][g];
    }
  if (kg == 0) unsafeAtomicAdd(&sg[wv * 16 + l15], accs[0]);
}

// ---------------------------------------------------------------------------
// K_gred: G = sum over partials.  grid 64 x 256.
// ---------------------------------------------------------------------------
__global__ __launch_bounds__(256) void k_gred(
    const float* __restrict__ Gpart, float* __restrict__ G, int nb)
{
  int i = blockIdx.x * 256 + threadIdx.x;   // < 16384
  float s0 = 0.f, s1 = 0.f, s2 = 0.f, s3 = 0.f;
  for (int p = 0; p < nb; p += 4) {
    s0 += Gpart[(size_t)p * 16384 + i];
    s1 += Gpart[(size_t)(p + 1) * 16384 + i];
    s2 += Gpart[(size_t)(p + 2) * 16384 + i];
    s3 += Gpart[(size_t)(p + 3) * 16384 + i];
  }
  G[i] = (s0 + s1) + (s2 + s3);
}

// ---------------------------------------------------------------------------
// K_statfin: stats from G and s.  w' = W_m[:,c] + e_c.
//   sum[c] = s·w' + N b ;  ssq[c] = w'^T G w' + 2b(s·w') + N b^2.
// grid 12 x 512: 32 outputs/block, 16 lanes per output.
// ---------------------------------------------------------------------------
__global__ __launch_bounds__(512) void k_statfin(
    const float* __restrict__ G, const float* __restrict__ sg,
    const float* __restrict__ Ws, const float* __restrict__ Wi,
    const float* __restrict__ Wr,
    const float* __restrict__ bs, const float* __restrict__ bi,
    const float* __restrict__ br,
    float* __restrict__ stats, int N)
{
  __shared__ float wls[32][128];
  const int tid = threadIdx.x;
  const int lo = tid >> 4;              // local output 0..31
  const int j  = tid & 15;
  const int out = blockIdx.x * 32 + lo; // < 384
  const int m = out >> 7, c = out & 127;
  const float* W = (m == 0) ? Ws : ((m == 1) ? Wi : Wr);

#pragma unroll
  for (int i = 0; i < 8; i++) {
    int k = j + i * 16;
    wls[lo][k] = W[(size_t)k * 128 + c] + (k == c ? 1.f : 0.f);
  }
  __syncthreads();

  float pv = 0.f, ps = 0.f;
#pragma unroll
  for (int i = 0; i < 8; i++) {
    int k = j + i * 16;
    float wk = wls[lo][k];
    ps += sg[k] * wk;
    float dot = 0.f;
#pragma unroll 4
    for (int kk = 0; kk < 128; kk++)
      dot = fmaf(G[k * 128 + kk], wls[lo][kk], dot);
    pv = fmaf(wk, dot, pv);
  }
#pragma unroll
  for (int off = 1; off < 16; off <<= 1) {
    pv += __shfl_xor(pv, off);
    ps += __shfl_xor(ps, off);
  }
  if (j == 0) {
    const float* B = (m == 0) ? bs : ((m == 1) ? bi : br);
    float b = B[c];
    stats[m * 256 + c] = ps + (float)N * b;
    stats[m * 256 + 128 + c] = pv + 2.f * b * ps + (float)N * b * b;
  }
}

// ---------------------------------------------------------------------------
// K_bnscale: blocks 0..23: W'' = (W+I)·diag(a_m) split-bf16 (fragment order).
// Block 24: kvec[m][c] = a·(bias_m[c] − μ) + β.  a = γ·rsqrt(var+ε).
// ---------------------------------------------------------------------------
__global__ __launch_bounds__(256) void k_bnscale(
    const float* __restrict__ Ws, const float* __restrict__ Wi,
    const float* __restrict__ Wr,
    const float* __restrict__ bs, const float* __restrict__ bi,
    const float* __restrict__ br,
    const float* __restrict__ gamma, const float* __restrict__ beta,
    const float* __restrict__ stats,
    short* __restrict__ Whi2, short* __restrict__ Wlo2,
    float* __restrict__ kvec, float invN)
{
  const int tid = threadIdx.x;
  if (blockIdx.x < 24) {
    int t = blockIdx.x * 256 + tid;
    int m   = t >> 11;
    int rem = t & 2047;
    int kf  = rem >> 9;
    int kg  = (rem >> 7) & 3;
    int c   = rem & 127;
    const float* W = (m == 0) ? Ws : ((m == 1) ? Wi : Wr);
    float mu = stats[m * 256 + c] * invN;
    float var = stats[m * 256 + 128 + c] * invN - mu * mu;
    float a = gamma[c] * rsqrtf(var + EPSBN);
    short hb[8], lb[8];
#pragma unroll
    for (int j = 0; j < 8; j++) {
      int k = kf * 32 + kg * 8 + j;
      float w = (W[(size_t)k * NFEAT + c] + (k == c ? 1.0f : 0.0f)) * a;
      unsigned short h = f2bf(w);
      hb[j] = (short)h;
      lb[j] = (short)f2bf(w - bf2f(h));
    }
    int base = ((m * 16 + kf * 4 + kg) << 10) + (c << 3);
    *(short8*)&Whi2[base] = *(short8*)hb;
    *(short8*)&Wlo2[base] = *(short8*)lb;
    return;
  }
  if (tid < 384) {
    int m = tid >> 7, c = tid & 127;
    const float* B = (m == 0) ? bs : ((m == 1) ? bi : br);
    float mu = stats[m * 256 + c] * invN;
    float var = stats[m * 256 + 128 + c] * invN - mu * mu;
    float a = gamma[c] * rsqrtf(var + EPSBN);
    kvec[m * 128 + c] = a * (B[c] - mu) + beta[c];
  }
}

// ---------------------------------------------------------------------------
// K1f: fused main pass.  Wave owns 16 rows x 128 cols; 8 waves/block.
// Per m: stage W''_m hi/lo into LDS; cg pairs with 6 independent MFMA chains.
// MT/kvec staged in LDS (epilogue reads were L2-latency-bound scalar loads).
// v = relu(acc + kvec); fold into slog/q partials.  Zeroes logit3R rows.
// ---------------------------------------------------------------------------
__global__ __launch_bounds__(512, 2) void k1f_fused(
    const float* __restrict__ feat,
    const short* __restrict__ Whi2, const short* __restrict__ Wlo2,
    const float* __restrict__ MT, const float* __restrict__ kvec,
    float* __restrict__ slogA, float* __restrict__ qv,
    float* __restrict__ logit3R, int N, int N4)
{
  __shared__ short Bh[16384];   // 32 KB
  __shared__ short Bl[16384];   // 32 KB
  __shared__ float MTs[1536];
  __shared__ float kvs[384];

  const int tid  = threadIdx.x;
  const int lane = tid & 63;
  const int wv   = tid >> 6;
  const int kg   = lane >> 4;
  const int l15  = lane & 15;

  // stage MT/kvec; zero logit3R for this block's 128 rows x NREP reps
  for (int i = tid; i < 1536; i += 512) MTs[i] = MT[i];
  if (tid < 384) kvs[tid] = kvec[tid];
  {
    int base_r = blockIdx.x * 128;
#pragma unroll
    for (int i = 0; i < 2; i++) {
      int idx = i * 512 + tid;
      int rep = idx >> 7;
      int ro  = idx & 127;
      int r = base_r + ro;
      if (r < N)
        *(float4*)&logit3R[(size_t)rep * N4 + (size_t)r * 4] =
            make_float4(0.f, 0.f, 0.f, 0.f);
    }
  }

  const int rowbase = blockIdx.x * 128 + wv * 16;

  // A fragments (16 rows, split-bf16): 8 short8 = 32 VGPR
  short8 ah[4], al[4];
  {
    int r = rowbase + l15; if (r >= N) r = N - 1;
    const float4* fp = (const float4*)(feat + (size_t)r * NFEAT);
#pragma unroll
    for (int kf = 0; kf < 4; kf++) {
      float4 x0 = fp[kf * 8 + kg * 2];
      float4 x1 = fp[kf * 8 + kg * 2 + 1];
      float xs[8] = {x0.x, x0.y, x0.z, x0.w, x1.x, x1.y, x1.z, x1.w};
      short hb[8], lb[8];
#pragma unroll
      for (int j = 0; j < 8; j++) {
        unsigned short h = f2bf(xs[j]);
        hb[j] = (short)h;
        lb[j] = (short)f2bf(xs[j] - bf2f(h));
      }
      ah[kf] = *(short8*)hb;
      al[kf] = *(short8*)lb;
    }
  }

  float sac[4][3];
  float qac[4][3];
#pragma unroll
  for (int g = 0; g < 4; g++)
#pragma unroll
    for (int cl = 0; cl < 3; cl++) { sac[g][cl] = 0.f; qac[g][cl] = 0.f; }

  for (int m = 0; m < 3; m++) {
    __syncthreads();   // previous m's readers done (also covers MTs staging)
    {
      const short8* gh = (const short8*)(Whi2 + (m << 14));
      const short8* gl = (const short8*)(Wlo2 + (m << 14));
      short8* lh = (short8*)Bh;
      short8* ll = (short8*)Bl;
#pragma unroll
      for (int q = 0; q < 4; q++) {
        int slot = q * 512 + tid;
        lh[slot] = gh[slot];
        ll[slot] = gl[slot];
      }
    }
    __syncthreads();

#pragma unroll
    for (int cgp = 0; cgp < 4; cgp++) {
      const int cg0 = cgp * 2, cg1 = cgp * 2 + 1;
      f32x4 aA0 = {0.f,0.f,0.f,0.f}, aB0 = {0.f,0.f,0.f,0.f}, aC0 = {0.f,0.f,0.f,0.f};
      f32x4 aA1 = {0.f,0.f,0.f,0.f}, aB1 = {0.f,0.f,0.f,0.f}, aC1 = {0.f,0.f,0.f,0.f};
#pragma unroll
      for (int kf = 0; kf < 4; kf++) {
        int base0 = ((kf * 4 + kg) << 10) + ((cg0 * 16 + l15) << 3);
        int base1 = ((kf * 4 + kg) << 10) + ((cg1 * 16 + l15) << 3);
        short8 bh0 = *(const short8*)&Bh[base0];
        short8 bl0 = *(const short8*)&Bl[base0];
        short8 bh1 = *(const short8*)&Bh[base1];
        short8 bl1 = *(const short8*)&Bl[base1];
        aA0 = __builtin_amdgcn_mfma_f32_16x16x32_bf16(ah[kf], bh0, aA0, 0, 0, 0);
        aA1 = __builtin_amdgcn_mfma_f32_16x16x32_bf16(ah[kf], bh1, aA1, 0, 0, 0);
        aB0 = __builtin_amdgcn_mfma_f32_16x16x32_bf16(al[kf], bh0, aB0, 0, 0, 0);
        aB1 = __builtin_amdgcn_mfma_f32_16x16x32_bf16(al[kf], bh1, aB1, 0, 0, 0);
        aC0 = __builtin_amdgcn_mfma_f32_16x16x32_bf16(ah[kf], bl0, aC0, 0, 0, 0);
        aC1 = __builtin_amdgcn_mfma_f32_16x16x32_bf16(ah[kf], bl1, aC1, 0, 0, 0);
      }
#pragma unroll
      for (int s = 0; s < 2; s++) {
        int c = (s == 0 ? cg0 : cg1) * 16 + l15;
        f32x4 aA = s == 0 ? aA0 : aA1;
        f32x4 aB = s == 0 ? aB0 : aB1;
        f32x4 aC = s == 0 ? aC0 : aC1;
        float kc  = kvs[m * 128 + c];
        float mt0 = MTs[0 * 512 + m * 128 + c];
        float mt1 = MTs[1 * 512 + m * 128 + c];
        float mt2 = MTs[2 * 512 + m * 128 + c];
        if (m == 1) {
          float mq0 = MTs[0 * 512 + 384 + c];
          float mq1 = MTs[1 * 512 + 384 + c];
          float mq2 = MTs[2 * 512 + 384 + c];
#pragma unroll
          for (int g = 0; g < 4; g++) {
            float v = fmaxf(aA[g] + aB[g] + aC[g] + kc, 0.f);
            sac[g][0] = fmaf(v, mt0, sac[g][0]);
            sac[g][1] = fmaf(v, mt1, sac[g][1]);
            sac[g][2] = fmaf(v, mt2, sac[g][2]);
            qac[g][0] = fmaf(v, mq0, qac[g][0]);
            qac[g][1] = fmaf(v, mq1, qac[g][1]);
            qac[g][2] = fmaf(v, mq2, qac[g][2]);
          }
        } else {
#pragma unroll
          for (int g = 0; g < 4; g++) {
            float v = fmaxf(aA[g] + aB[g] + aC[g] + kc, 0.f);
            sac[g][0] = fmaf(v, mt0, sac[g][0]);
            sac[g][1] = fmaf(v, mt1, sac[g][1]);
            sac[g][2] = fmaf(v, mt2, sac[g][2]);
          }
        }
      }
    }
  }

#pragma unroll
  for (int g = 0; g < 4; g++) {
    float s0 = sac[g][0], s1 = sac[g][1], s2 = sac[g][2];
    float q0 = qac[g][0], q1 = qac[g][1], q2 = qac[g][2];
#pragma unroll
    for (int off = 1; off < 16; off <<= 1) {
      s0 += __shfl_xor(s0, off); s1 += __shfl_xor(s1, off);
      s2 += __shfl_xor(s2, off);
      q0 += __shfl_xor(q0, off); q1 += __shfl_xor(q1, off);
      q2 += __shfl_xor(q2, off);
    }
    if (l15 == 0) {
      int r = rowbase + kg * 4 + g;
      if (r < N) {
        *(float4*)&slogA[(size_t)r * 4] = make_float4(s0, s1, s2, 0.f);
        *(float4*)&qv[(size_t)r * 4]    = make_float4(q0, q1, q2, 0.f);
      }
    }
  }
}

// ---------------------------------------------------------------------------
// K_edge: 64 lanes = 21 edges x 3 comps; one atomic/lane, same-line merge,
// replica (waveID&7) spreads contention.
// ---------------------------------------------------------------------------
__global__ __launch_bounds__(256) void k_edge(
    const int* __restrict__ eidx, const float* __restrict__ ew,
    const float* __restrict__ q, float* __restrict__ logit3R,
    int E, int N4)
{
  const int wid  = (blockIdx.x * 256 + threadIdx.x) >> 6;
  const int lane = threadIdx.x & 63;
  const int el   = lane / 3;
  const int comp = lane - el * 3;
  if (el >= 21) return;
  const int e = wid * 21 + el;
  if (e >= E) return;

  int src = eidx[e];
  int dst = eidx[E + e];
  float w = ew[e];
  float qvv = q[(size_t)src * 4 + comp];
  int rep = wid & (NREP - 1);
  unsafeAtomicAdd(&logit3R[(size_t)rep * N4 + (size_t)dst * 4 + comp], qvv * w);
}

// ---------------------------------------------------------------------------
// K4t: out[r] = softmax(slog[r] + sum_rep logit3R[rep][r] + cb).
// ---------------------------------------------------------------------------
__global__ __launch_bounds__(256) void k4_final(
    const float* __restrict__ slogA, const float* __restrict__ logit3R,
    const float* __restrict__ cb,
    float* __restrict__ out, int N, int N4)
{
  int r = blockIdx.x * 256 + threadIdx.x;
  if (r >= N) return;
  float4 S = *(const float4*)&slogA[(size_t)r * 4];
  float l0 = S.x + cb[0], l1 = S.y + cb[1], l2 = S.z + cb[2];
#pragma unroll
  for (int rep = 0; rep < NREP; rep++) {
    float4 L = *(const float4*)&logit3R[(size_t)rep * N4 + (size_t)r * 4];
    l0 += L.x; l1 += L.y; l2 += L.z;
  }
  float mx = fmaxf(l0, fmaxf(l1, l2));
  float e0 = expf(l0 - mx), e1 = expf(l1 - mx), e2 = expf(l2 - mx);
  float inv = 1.f / (e0 + e1 + e2);
  out[(size_t)r * 3 + 0] = e0 * inv;
  out[(size_t)r * 3 + 1] = e1 * inv;
  out[(size_t)r * 3 + 2] = e2 * inv;
}

// ---------------------------------------------------------------------------
extern "C" void kernel_launch(void* const* d_in, const int* in_sizes, int n_in,
                              void* d_out, int out_size, void* d_ws, size_t ws_size,
                              hipStream_t stream)
{
  const float* feat  = (const float*)d_in[0];
  const int*   eidx  = (const int*)  d_in[1];
  const float* ew    = (const float*)d_in[2];
  const float* Ws    = (const float*)d_in[3];
  const float* bs    = (const float*)d_in[4];
  const float* Wi    = (const float*)d_in[5];
  const float* bi    = (const float*)d_in[6];
  const float* Wr    = (const float*)d_in[7];
  const float* br    = (const float*)d_in[8];
  const float* gamma = (const float*)d_in[9];
  const float* beta  = (const float*)d_in[10];
  const float* WtoI  = (const float*)d_in[11];
  const float* btoI  = (const float*)d_in[12];
  const float* WtoR  = (const float*)d_in[13];
  const float* btoR  = (const float*)d_in[14];
  const float* Wout  = (const float*)d_in[15];
  const float* bout  = (const float*)d_in[16];

  const int N = in_sizes[0] / NFEAT;
  const int E = in_sizes[2];
  const int N4 = 4 * N;
  const float invN = 1.0f / (float)N;
  float* out = (float*)d_out;

  const int GGRID = 512;                         // k_gram blocks

  float* logit3R = (float*)d_ws;                 // NREP*4*N
  float* slogA   = logit3R + (size_t)NREP * N4;  // 4*N
  float* qv      = slogA + 4 * (size_t)N;        // 4*N
  float* stats   = qv + 4 * (size_t)N;           // 768
  float* MT      = stats + 768;                  // 1536
  float* cb      = MT + 1536;                    // 4
  float* kvec    = cb + 4;                       // 384
  float* sg      = kvec + 384;                   // 128
  float* G       = sg + 128;                     // 16384
  short* Whi2    = (short*)(G + 16384);          // 49152
  short* Wlo2    = Whi2 + 49152;                 // 49152
  float* Gpart   = (float*)(Wlo2 + 49152);       // GGRID*16384

  hipMemsetAsync(sg, 0, 128 * sizeof(float), stream);

  const int nt64 = (N + 63) / 64;                // 1563

  kp_fold<<<6, 256, 0, stream>>>(WtoI, btoI, WtoR, btoR, Wout, bout, MT, cb);
  k_gram<<<GGRID, 512, 0, stream>>>(feat, Gpart, sg, N, nt64);
  k_gred<<<64, 256, 0, stream>>>(Gpart, G, GGRID);
  k_statfin<<<12, 512, 0, stream>>>(G, sg, Ws, Wi, Wr, bs, bi, br, stats, N);
  k_bnscale<<<25, 256, 0, stream>>>(Ws, Wi, Wr, bs, bi, br, gamma, beta,
                                    stats, Whi2, Wlo2, kvec, invN);
  const int gf = (N + 127) / 128;                // 782
  k1f_fused<<<gf, 512, 0, stream>>>(feat, Whi2, Wlo2, MT, kvec,
                                    slogA, qv, logit3R, N, N4);
  const int nwaves = (E + 20) / 21;
  k_edge<<<(nwaves + 3) / 4, 256, 0, stream>>>(eidx, ew, qv, logit3R, E, N4);
  k4_final<<<(N + 255) / 256, 256, 0, stream>>>(slogA, logit3R, cb, out, N, N4);
}

// Round 16
// 169.135 us; speedup vs baseline: 1.5958x; 1.5958x over previous
//
#include <hip/hip_runtime.h>
#include <math.h>

#define NFEAT 128
#define EPSBN 1e-5f
#define LDA 136   // bf16 elems per LDS row: 128 + 8 pad
#define NREP 8    // logit3 replicas to spread atomic contention

typedef __attribute__((ext_vector_type(8))) short short8;
typedef __attribute__((ext_vector_type(4))) float f32x4;

__device__ __forceinline__ unsigned short f2bf(float x) {
  union { float f; unsigned u; } v; v.f = x;
  unsigned r = v.u + 0x7FFF + ((v.u >> 16) & 1);   // RNE
  return (unsigned short)(r >> 16);
}
__device__ __forceinline__ float bf2f(unsigned short h) {
  union { unsigned u; float f; } v; v.u = (unsigned)h << 16;
  return v.f;
}

// ---------------------------------------------------------------------------
// KP: blocks 0..23: split W' = (W + I) into bf16 hi/lo planes in MFMA
// B-fragment order (for the stats pass).  Blocks 24..29: fold back-half into
// MT + cb.  logits = S@M1 + I@M3 + R@M4 + NB@M2 + cb.
// MT layout: MT[cl*512 + part*128 + k], part: 0=S 1=I 2=R 3=NB.
// ---------------------------------------------------------------------------
__global__ __launch_bounds__(256) void kp_params(
    const float* __restrict__ Ws, const float* __restrict__ Wi,
    const float* __restrict__ Wr,
    const float* __restrict__ WtoI, const float* __restrict__ btoI,
    const float* __restrict__ WtoR, const float* __restrict__ btoR,
    const float* __restrict__ Wout, const float* __restrict__ bout,
    short* __restrict__ Whi, short* __restrict__ Wlo,
    float* __restrict__ MT, float* __restrict__ cb)
{
  const int tid = threadIdx.x;
  if (blockIdx.x < 24) {
    int t = blockIdx.x * 256 + tid;   // 6144 total
    int m   = t >> 11;
    int rem = t & 2047;
    int kf  = rem >> 9;
    int kg  = (rem >> 7) & 3;
    int c   = rem & 127;
    const float* W = (m == 0) ? Ws : ((m == 1) ? Wi : Wr);
    short hb[8], lb[8];
#pragma unroll
    for (int j = 0; j < 8; j++) {
      int k = kf * 32 + kg * 8 + j;
      float w = W[(size_t)k * NFEAT + c] + (k == c ? 1.0f : 0.0f);
      unsigned short h = f2bf(w);
      hb[j] = (short)h;
      lb[j] = (short)f2bf(w - bf2f(h));
    }
    int base = ((m * 16 + kf * 4 + kg) << 10) + (c << 3);
    *(short8*)&Whi[base] = *(short8*)hb;
    *(short8*)&Wlo[base] = *(short8*)lb;
    return;
  }

  int t = (blockIdx.x - 24) * 256 + tid;   // 0..1535
  int cl = t / 512;
  int idx = t - cl * 512;
  int part = idx >> 7, k = idx & 127;
  float val;
  if (part == 0) {            // S: Wo1 + WtoI_top @ (Wo2-Wo1)
    float s = Wout[k * 3 + cl];
    for (int f = 0; f < 128; f++)
      s = fmaf(WtoI[k * 128 + f],
               Wout[(128 + f) * 3 + cl] - Wout[f * 3 + cl], s);
    val = s;
  } else if (part == 1) {     // I: Wo2 + WtoR @ (Wo3-Wo2)
    float s = Wout[(128 + k) * 3 + cl];
    for (int f = 0; f < 128; f++)
      s = fmaf(WtoR[k * 128 + f],
               Wout[(256 + f) * 3 + cl] - Wout[(128 + f) * 3 + cl], s);
    val = s;
  } else if (part == 2) {     // R: Wo3
    val = Wout[(256 + k) * 3 + cl];
  } else {                    // NB: WtoI_bot @ (Wo2-Wo1)
    float s = 0.f;
    for (int f = 0; f < 128; f++)
      s = fmaf(WtoI[(128 + k) * 128 + f],
               Wout[(128 + f) * 3 + cl] - Wout[f * 3 + cl], s);
    val = s;
  }
  MT[cl * 512 + idx] = val;

  if (blockIdx.x == 24 && tid < 3) {
    float s = bout[tid];
    for (int f = 0; f < 128; f++) {
      s = fmaf(btoI[f], Wout[(128 + f) * 3 + tid] - Wout[f * 3 + tid], s);
      s = fmaf(btoR[f], Wout[(256 + f) * 3 + tid] - Wout[(128 + f) * 3 + tid], s);
    }
    cb[tid] = s;
  }
}

// ---------------------------------------------------------------------------
// K1a (stats-only GEMM): column sum/sumsq of P_w = feat @ (W_w+I) + b_w.
// ---------------------------------------------------------------------------
__global__ __launch_bounds__(512, 2) void k1a_stats(
    const float* __restrict__ feat,
    const short* __restrict__ Whi, const short* __restrict__ Wlo,
    const float* __restrict__ bs, const float* __restrict__ bi,
    const float* __restrict__ br,
    float* __restrict__ stats,   // 6*128
    int N, int ntiles)
{
  __shared__ short Ah[2][64 * LDA];
  __shared__ short Al[2][64 * LDA];

  const int tid  = threadIdx.x;
  const int lane = tid & 63;
  const int wv   = tid >> 6;
  const int colb = wv * 16 + (lane & 15);
  const int kg   = lane >> 4;
  const int krow = kg * 8;

  const int sr = tid >> 3;
  const int so = tid & 7;

  const float bias[3] = {bs[colb], bi[colb], br[colb]};
  float ssum[3] = {0.f, 0.f, 0.f}, ssq[3] = {0.f, 0.f, 0.f};

  float4 pf[4];
  {
    int gr = blockIdx.x * 64 + sr; if (gr >= N) gr = N - 1;
    const float4* s4 = (const float4*)(feat + (size_t)gr * NFEAT + so * 16);
#pragma unroll
    for (int q = 0; q < 4; q++) pf[q] = s4[q];
    short hbuf[16], lbuf[16];
#pragma unroll
    for (int q = 0; q < 4; q++) {
      float xs[4] = {pf[q].x, pf[q].y, pf[q].z, pf[q].w};
#pragma unroll
      for (int cc = 0; cc < 4; cc++) {
        unsigned short h = f2bf(xs[cc]);
        hbuf[q * 4 + cc] = (short)h;
        lbuf[q * 4 + cc] = (short)f2bf(xs[cc] - bf2f(h));
      }
    }
    *(short8*)&Ah[0][sr * LDA + so * 16]     = *(short8*)(hbuf);
    *(short8*)&Ah[0][sr * LDA + so * 16 + 8] = *(short8*)(hbuf + 8);
    *(short8*)&Al[0][sr * LDA + so * 16]     = *(short8*)(lbuf);
    *(short8*)&Al[0][sr * LDA + so * 16 + 8] = *(short8*)(lbuf + 8);
  }
  __syncthreads();

  int cur = 0;
  for (int tile = blockIdx.x; tile < ntiles; tile += gridDim.x) {
    const int row0 = tile * 64;
    const int ntile = tile + gridDim.x;
    const bool have_next = ntile < ntiles;

    if (have_next) {
      int gr = ntile * 64 + sr; if (gr >= N) gr = N - 1;
      const float4* s4 = (const float4*)(feat + (size_t)gr * NFEAT + so * 16);
#pragma unroll
      for (int q = 0; q < 4; q++) pf[q] = s4[q];
    }

    const short* ah_c = &Ah[cur][0];
    const short* al_c = &Al[cur][0];

    f32x4 acc[3][4];
#pragma unroll
    for (int m = 0; m < 3; m++)
#pragma unroll
      for (int rf = 0; rf < 4; rf++)
        acc[m][rf] = (f32x4){0.f, 0.f, 0.f, 0.f};

#pragma unroll
    for (int kf = 0; kf < 4; kf++) {
      short8 bh[3], bl[3];
#pragma unroll
      for (int m = 0; m < 3; m++) {
        int fb = ((m * 16 + kf * 4 + kg) << 10) + (colb << 3);
        bh[m] = *(const short8*)&Whi[fb];
        bl[m] = *(const short8*)&Wlo[fb];
      }
      short8 ah[4], al[4];
#pragma unroll
      for (int rf = 0; rf < 4; rf++) {
        int off = (rf * 16 + (lane & 15)) * LDA + kf * 32 + krow;
        ah[rf] = *(const short8*)&ah_c[off];
        al[rf] = *(const short8*)&al_c[off];
      }
#pragma unroll
      for (int m = 0; m < 3; m++) {
#pragma unroll
        for (int rf = 0; rf < 4; rf++) {
          acc[m][rf] = __builtin_amdgcn_mfma_f32_16x16x32_bf16(
              ah[rf], bh[m], acc[m][rf], 0, 0, 0);
          acc[m][rf] = __builtin_amdgcn_mfma_f32_16x16x32_bf16(
              al[rf], bh[m], acc[m][rf], 0, 0, 0);
          acc[m][rf] = __builtin_amdgcn_mfma_f32_16x16x32_bf16(
              ah[rf], bl[m], acc[m][rf], 0, 0, 0);
        }
      }
    }

    // stats only (residual already in W' via +I)
#pragma unroll
    for (int rf = 0; rf < 4; rf++) {
      int lrb = rf * 16 + kg * 4;
#pragma unroll
      for (int g = 0; g < 4; g++) {
        bool ok = (row0 + lrb + g) < N;
#pragma unroll
        for (int m = 0; m < 3; m++) {
          float v = acc[m][rf][g] + bias[m];
          if (ok) { ssum[m] += v; ssq[m] += v * v; }
        }
      }
    }

    if (have_next) {
      short hbuf[16], lbuf[16];
#pragma unroll
      for (int q = 0; q < 4; q++) {
        float xs[4] = {pf[q].x, pf[q].y, pf[q].z, pf[q].w};
#pragma unroll
        for (int cc = 0; cc < 4; cc++) {
          unsigned short h = f2bf(xs[cc]);
          hbuf[q * 4 + cc] = (short)h;
          lbuf[q * 4 + cc] = (short)f2bf(xs[cc] - bf2f(h));
        }
      }
      int nb = cur ^ 1;
      *(short8*)&Ah[nb][sr * LDA + so * 16]     = *(short8*)(hbuf);
      *(short8*)&Ah[nb][sr * LDA + so * 16 + 8] = *(short8*)(hbuf + 8);
      *(short8*)&Al[nb][sr * LDA + so * 16]     = *(short8*)(lbuf);
      *(short8*)&Al[nb][sr * LDA + so * 16 + 8] = *(short8*)(lbuf + 8);
    }
    __syncthreads();
    cur ^= 1;
  }

#pragma unroll
  for (int m = 0; m < 3; m++) {
    float s = ssum[m], q = ssq[m];
    s += __shfl_xor(s, 16); s += __shfl_xor(s, 32);
    q += __shfl_xor(q, 16); q += __shfl_xor(q, 32);
    if (kg == 0) {
      unsafeAtomicAdd(&stats[m * 256 + colb], s);
      unsafeAtomicAdd(&stats[m * 256 + 128 + colb], q);
    }
  }
}

// ---------------------------------------------------------------------------
// K_bnscale: blocks 0..23: W'' = (W+I)·diag(a_m) split-bf16 (fragment order).
// Block 24: kvec[m][c] = a·(bias_m[c] − μ) + β.  a = γ·rsqrt(var+ε).
// ---------------------------------------------------------------------------
__global__ __launch_bounds__(256) void k_bnscale(
    const float* __restrict__ Ws, const float* __restrict__ Wi,
    const float* __restrict__ Wr,
    const float* __restrict__ bs, const float* __restrict__ bi,
    const float* __restrict__ br,
    const float* __restrict__ gamma, const float* __restrict__ beta,
    const float* __restrict__ stats,
    short* __restrict__ Whi2, short* __restrict__ Wlo2,
    float* __restrict__ kvec, float invN)
{
  const int tid = threadIdx.x;
  if (blockIdx.x < 24) {
    int t = blockIdx.x * 256 + tid;
    int m   = t >> 11;
    int rem = t & 2047;
    int kf  = rem >> 9;
    int kg  = (rem >> 7) & 3;
    int c   = rem & 127;
    const float* W = (m == 0) ? Ws : ((m == 1) ? Wi : Wr);
    float mu = stats[m * 256 + c] * invN;
    float var = stats[m * 256 + 128 + c] * invN - mu * mu;
    float a = gamma[c] * rsqrtf(var + EPSBN);
    short hb[8], lb[8];
#pragma unroll
    for (int j = 0; j < 8; j++) {
      int k = kf * 32 + kg * 8 + j;
      float w = (W[(size_t)k * NFEAT + c] + (k == c ? 1.0f : 0.0f)) * a;
      unsigned short h = f2bf(w);
      hb[j] = (short)h;
      lb[j] = (short)f2bf(w - bf2f(h));
    }
    int base = ((m * 16 + kf * 4 + kg) << 10) + (c << 3);
    *(short8*)&Whi2[base] = *(short8*)hb;
    *(short8*)&Wlo2[base] = *(short8*)lb;
    return;
  }
  if (tid < 384) {
    int m = tid >> 7, c = tid & 127;
    const float* B = (m == 0) ? bs : ((m == 1) ? bi : br);
    float mu = stats[m * 256 + c] * invN;
    float var = stats[m * 256 + 128 + c] * invN - mu * mu;
    float a = gamma[c] * rsqrtf(var + EPSBN);
    kvec[m * 128 + c] = a * (B[c] - mu) + beta[c];
  }
}

// ---------------------------------------------------------------------------
// K1f: fused main pass.  Wave owns 16 rows x 128 cols; 8 waves/block.
// Per m: stage W''_m hi/lo into LDS; cg pairs with 6 independent MFMA chains.
// v = relu(acc + kvec); fold into slog/q partials.  Zeroes logit3R rows.
// ---------------------------------------------------------------------------
__global__ __launch_bounds__(512, 2) void k1f_fused(
    const float* __restrict__ feat,
    const short* __restrict__ Whi2, const short* __restrict__ Wlo2,
    const float* __restrict__ MT, const float* __restrict__ kvec,
    float* __restrict__ slogA, float* __restrict__ qv,
    float* __restrict__ logit3R, int N, int N4)
{
  __shared__ short Bh[16384];   // 32 KB
  __shared__ short Bl[16384];   // 32 KB

  const int tid  = threadIdx.x;
  const int lane = tid & 63;
  const int wv   = tid >> 6;
  const int kg   = lane >> 4;
  const int l15  = lane & 15;

  // zero logit3R for this block's 128 rows x NREP reps
  {
    int base_r = blockIdx.x * 128;
#pragma unroll
    for (int i = 0; i < 2; i++) {
      int idx = i * 512 + tid;
      int rep = idx >> 7;
      int ro  = idx & 127;
      int r = base_r + ro;
      if (r < N)
        *(float4*)&logit3R[(size_t)rep * N4 + (size_t)r * 4] =
            make_float4(0.f, 0.f, 0.f, 0.f);
    }
  }

  const int rowbase = blockIdx.x * 128 + wv * 16;

  // A fragments (16 rows, split-bf16): 8 short8 = 32 VGPR
  short8 ah[4], al[4];
  {
    int r = rowbase + l15; if (r >= N) r = N - 1;
    const float4* fp = (const float4*)(feat + (size_t)r * NFEAT);
#pragma unroll
    for (int kf = 0; kf < 4; kf++) {
      float4 x0 = fp[kf * 8 + kg * 2];
      float4 x1 = fp[kf * 8 + kg * 2 + 1];
      float xs[8] = {x0.x, x0.y, x0.z, x0.w, x1.x, x1.y, x1.z, x1.w};
      short hb[8], lb[8];
#pragma unroll
      for (int j = 0; j < 8; j++) {
        unsigned short h = f2bf(xs[j]);
        hb[j] = (short)h;
        lb[j] = (short)f2bf(xs[j] - bf2f(h));
      }
      ah[kf] = *(short8*)hb;
      al[kf] = *(short8*)lb;
    }
  }

  float sac[4][3];
  float qac[4][3];
#pragma unroll
  for (int g = 0; g < 4; g++)
#pragma unroll
    for (int cl = 0; cl < 3; cl++) { sac[g][cl] = 0.f; qac[g][cl] = 0.f; }

  for (int m = 0; m < 3; m++) {
    __syncthreads();   // previous m's readers done
    {
      const short8* gh = (const short8*)(Whi2 + (m << 14));
      const short8* gl = (const short8*)(Wlo2 + (m << 14));
      short8* lh = (short8*)Bh;
      short8* ll = (short8*)Bl;
#pragma unroll
      for (int q = 0; q < 4; q++) {
        int slot = q * 512 + tid;
        lh[slot] = gh[slot];
        ll[slot] = gl[slot];
      }
    }
    __syncthreads();

#pragma unroll
    for (int cgp = 0; cgp < 4; cgp++) {
      const int cg0 = cgp * 2, cg1 = cgp * 2 + 1;
      f32x4 aA0 = {0.f,0.f,0.f,0.f}, aB0 = {0.f,0.f,0.f,0.f}, aC0 = {0.f,0.f,0.f,0.f};
      f32x4 aA1 = {0.f,0.f,0.f,0.f}, aB1 = {0.f,0.f,0.f,0.f}, aC1 = {0.f,0.f,0.f,0.f};
#pragma unroll
      for (int kf = 0; kf < 4; kf++) {
        int base0 = ((kf * 4 + kg) << 10) + ((cg0 * 16 + l15) << 3);
        int base1 = ((kf * 4 + kg) << 10) + ((cg1 * 16 + l15) << 3);
        short8 bh0 = *(const short8*)&Bh[base0];
        short8 bl0 = *(const short8*)&Bl[base0];
        short8 bh1 = *(const short8*)&Bh[base1];
        short8 bl1 = *(const short8*)&Bl[base1];
        aA0 = __builtin_amdgcn_mfma_f32_16x16x32_bf16(ah[kf], bh0, aA0, 0, 0, 0);
        aA1 = __builtin_amdgcn_mfma_f32_16x16x32_bf16(ah[kf], bh1, aA1, 0, 0, 0);
        aB0 = __builtin_amdgcn_mfma_f32_16x16x32_bf16(al[kf], bh0, aB0, 0, 0, 0);
        aB1 = __builtin_amdgcn_mfma_f32_16x16x32_bf16(al[kf], bh1, aB1, 0, 0, 0);
        aC0 = __builtin_amdgcn_mfma_f32_16x16x32_bf16(ah[kf], bl0, aC0, 0, 0, 0);
        aC1 = __builtin_amdgcn_mfma_f32_16x16x32_bf16(ah[kf], bl1, aC1, 0, 0, 0);
      }
#pragma unroll
      for (int s = 0; s < 2; s++) {
        int c = (s == 0 ? cg0 : cg1) * 16 + l15;
        f32x4 aA = s == 0 ? aA0 : aA1;
        f32x4 aB = s == 0 ? aB0 : aB1;
        f32x4 aC = s == 0 ? aC0 : aC1;
        float kc  = kvec[m * 128 + c];
        float mt0 = MT[0 * 512 + m * 128 + c];
        float mt1 = MT[1 * 512 + m * 128 + c];
        float mt2 = MT[2 * 512 + m * 128 + c];
        if (m == 1) {
          float mq0 = MT[0 * 512 + 384 + c];
          float mq1 = MT[1 * 512 + 384 + c];
          float mq2 = MT[2 * 512 + 384 + c];
#pragma unroll
          for (int g = 0; g < 4; g++) {
            float v = fmaxf(aA[g] + aB[g] + aC[g] + kc, 0.f);
            sac[g][0] = fmaf(v, mt0, sac[g][0]);
            sac[g][1] = fmaf(v, mt1, sac[g][1]);
            sac[g][2] = fmaf(v, mt2, sac[g][2]);
            qac[g][0] = fmaf(v, mq0, qac[g][0]);
            qac[g][1] = fmaf(v, mq1, qac[g][1]);
            qac[g][2] = fmaf(v, mq2, qac[g][2]);
          }
        } else {
#pragma unroll
          for (int g = 0; g < 4; g++) {
            float v = fmaxf(aA[g] + aB[g] + aC[g] + kc, 0.f);
            sac[g][0] = fmaf(v, mt0, sac[g][0]);
            sac[g][1] = fmaf(v, mt1, sac[g][1]);
            sac[g][2] = fmaf(v, mt2, sac[g][2]);
          }
        }
      }
    }
  }

#pragma unroll
  for (int g = 0; g < 4; g++) {
    float s0 = sac[g][0], s1 = sac[g][1], s2 = sac[g][2];
    float q0 = qac[g][0], q1 = qac[g][1], q2 = qac[g][2];
#pragma unroll
    for (int off = 1; off < 16; off <<= 1) {
      s0 += __shfl_xor(s0, off); s1 += __shfl_xor(s1, off);
      s2 += __shfl_xor(s2, off);
      q0 += __shfl_xor(q0, off); q1 += __shfl_xor(q1, off);
      q2 += __shfl_xor(q2, off);
    }
    if (l15 == 0) {
      int r = rowbase + kg * 4 + g;
      if (r < N) {
        *(float4*)&slogA[(size_t)r * 4] = make_float4(s0, s1, s2, 0.f);
        *(float4*)&qv[(size_t)r * 4]    = make_float4(q0, q1, q2, 0.f);
      }
    }
  }
}

// ---------------------------------------------------------------------------
// K_edge: 64 lanes = 21 edges x 3 comps; one atomic/lane, same-line merge,
// replica (waveID&7) spreads contention.
// ---------------------------------------------------------------------------
__global__ __launch_bounds__(256) void k_edge(
    const int* __restrict__ eidx, const float* __restrict__ ew,
    const float* __restrict__ q, float* __restrict__ logit3R,
    int E, int N4)
{
  const int wid  = (blockIdx.x * 256 + threadIdx.x) >> 6;
  const int lane = threadIdx.x & 63;
  const int el   = lane / 3;
  const int comp = lane - el * 3;
  if (el >= 21) return;
  const int e = wid * 21 + el;
  if (e >= E) return;

  int src = eidx[e];
  int dst = eidx[E + e];
  float w = ew[e];
  float qvv = q[(size_t)src * 4 + comp];
  int rep = wid & (NREP - 1);
  unsafeAtomicAdd(&logit3R[(size_t)rep * N4 + (size_t)dst * 4 + comp], qvv * w);
}

// ---------------------------------------------------------------------------
// K4t: out[r] = softmax(slog[r] + sum_rep logit3R[rep][r] + cb).
// ---------------------------------------------------------------------------
__global__ __launch_bounds__(256) void k4_final(
    const float* __restrict__ slogA, const float* __restrict__ logit3R,
    const float* __restrict__ cb,
    float* __restrict__ out, int N, int N4)
{
  int r = blockIdx.x * 256 + threadIdx.x;
  if (r >= N) return;
  float4 S = *(const float4*)&slogA[(size_t)r * 4];
  float l0 = S.x + cb[0], l1 = S.y + cb[1], l2 = S.z + cb[2];
#pragma unroll
  for (int rep = 0; rep < NREP; rep++) {
    float4 L = *(const float4*)&logit3R[(size_t)rep * N4 + (size_t)r * 4];
    l0 += L.x; l1 += L.y; l2 += L.z;
  }
  float mx = fmaxf(l0, fmaxf(l1, l2));
  float e0 = expf(l0 - mx), e1 = expf(l1 - mx), e2 = expf(l2 - mx);
  float inv = 1.f / (e0 + e1 + e2);
  out[(size_t)r * 3 + 0] = e0 * inv;
  out[(size_t)r * 3 + 1] = e1 * inv;
  out[(size_t)r * 3 + 2] = e2 * inv;
}

// ---------------------------------------------------------------------------
extern "C" void kernel_launch(void* const* d_in, const int* in_sizes, int n_in,
                              void* d_out, int out_size, void* d_ws, size_t ws_size,
                              hipStream_t stream)
{
  const float* feat  = (const float*)d_in[0];
  const int*   eidx  = (const int*)  d_in[1];
  const float* ew    = (const float*)d_in[2];
  const float* Ws    = (const float*)d_in[3];
  const float* bs    = (const float*)d_in[4];
  const float* Wi    = (const float*)d_in[5];
  const float* bi    = (const float*)d_in[6];
  const float* Wr    = (const float*)d_in[7];
  const float* br    = (const float*)d_in[8];
  const float* gamma = (const float*)d_in[9];
  const float* beta  = (const float*)d_in[10];
  const float* WtoI  = (const float*)d_in[11];
  const float* btoI  = (const float*)d_in[12];
  const float* WtoR  = (const float*)d_in[13];
  const float* btoR  = (const float*)d_in[14];
  const float* Wout  = (const float*)d_in[15];
  const float* bout  = (const float*)d_in[16];

  const int N = in_sizes[0] / NFEAT;
  const int E = in_sizes[2];
  const int N4 = 4 * N;
  const float invN = 1.0f / (float)N;
  float* out = (float*)d_out;

  float* logit3R = (float*)d_ws;                 // NREP*4*N
  float* slogA   = logit3R + (size_t)NREP * N4;  // 4*N
  float* qv      = slogA + 4 * (size_t)N;        // 4*N
  float* stats   = qv + 4 * (size_t)N;           // 768
  float* MT      = stats + 768;                  // 1536
  float* cb      = MT + 1536;                    // 4
  float* kvec    = cb + 4;                       // 384
  short* Whi     = (short*)(kvec + 384);         // 49152
  short* Wlo     = Whi + 49152;                  // 49152
  short* Whi2    = Wlo + 49152;                  // 49152
  short* Wlo2    = Whi2 + 49152;                 // 49152

  hipMemsetAsync(stats, 0, 768 * sizeof(float), stream);

  const int nt = (N + 63) / 64;           // 1563
  const int g1 = (nt + 2) / 3;            // 521

  kp_params<<<30, 256, 0, stream>>>(Ws, Wi, Wr, WtoI, btoI, WtoR, btoR,
                                    Wout, bout, Whi, Wlo, MT, cb);
  k1a_stats<<<g1, 512, 0, stream>>>(feat, Whi, Wlo, bs, bi, br, stats, N, nt);
  k_bnscale<<<25, 256, 0, stream>>>(Ws, Wi, Wr, bs, bi, br, gamma, beta,
                                    stats, Whi2, Wlo2, kvec, invN);
  const int gf = (N + 127) / 128;         // 782
  k1f_fused<<<gf, 512, 0, stream>>>(feat, Whi2, Wlo2, MT, kvec,
                                    slogA, qv, logit3R, N, N4);
  const int nwaves = (E + 20) / 21;
  k_edge<<<(nwaves + 3) / 4, 256, 0, stream>>>(eidx, ew, qv, logit3R, E, N4);
  k4_final<<<(N + 255) / 256, 256, 0, stream>>>(slogA, logit3R, cb, out, N, N4);
}

// Round 18
// 168.277 us; speedup vs baseline: 1.6039x; 1.0051x over previous
//
#include <hip/hip_runtime.h>
#include <math.h>

#define NFEAT 128
#define EPSBN 1e-5f
#define LDA 136   // bf16 elems per LDS row: 128 + 8 pad
#define NREP 8    // logit3 replicas to spread atomic contention

typedef __attribute__((ext_vector_type(8))) short short8;
typedef __attribute__((ext_vector_type(4))) float f32x4;

__device__ __forceinline__ unsigned short f2bf(float x) {
  union { float f; unsigned u; } v; v.f = x;
  unsigned r = v.u + 0x7FFF + ((v.u >> 16) & 1);   // RNE
  return (unsigned short)(r >> 16);
}
__device__ __forceinline__ float bf2f(unsigned short h) {
  union { unsigned u; float f; } v; v.u = (unsigned)h << 16;
  return v.f;
}

// ---------------------------------------------------------------------------
// KP: blocks 0..23: split W' = (W + I) into bf16 hi/lo planes in MFMA
// B-fragment order.  Blocks 24..29: fold back-half into MT + cb.
//   logits = S@M1 + I@M3 + R@M4 + NB@M2 + cb
// MT layout: MT[cl*512 + part*128 + k], part: 0=S 1=I 2=R 3=NB.
// ---------------------------------------------------------------------------
__global__ __launch_bounds__(256) void kp_params(
    const float* __restrict__ Ws, const float* __restrict__ Wi,
    const float* __restrict__ Wr,
    const float* __restrict__ WtoI, const float* __restrict__ btoI,
    const float* __restrict__ WtoR, const float* __restrict__ btoR,
    const float* __restrict__ Wout, const float* __restrict__ bout,
    short* __restrict__ Whi, short* __restrict__ Wlo,
    float* __restrict__ MT, float* __restrict__ cb)
{
  const int tid = threadIdx.x;
  if (blockIdx.x < 24) {
    int t = blockIdx.x * 256 + tid;   // 6144 total
    int m   = t >> 11;
    int rem = t & 2047;
    int kf  = rem >> 9;
    int kg  = (rem >> 7) & 3;
    int c   = rem & 127;
    const float* W = (m == 0) ? Ws : ((m == 1) ? Wi : Wr);
    short hb[8], lb[8];
#pragma unroll
    for (int j = 0; j < 8; j++) {
      int k = kf * 32 + kg * 8 + j;
      float w = W[(size_t)k * NFEAT + c] + (k == c ? 1.0f : 0.0f);
      unsigned short h = f2bf(w);
      hb[j] = (short)h;
      lb[j] = (short)f2bf(w - bf2f(h));
    }
    int base = ((m * 16 + kf * 4 + kg) << 10) + (c << 3);
    *(short8*)&Whi[base] = *(short8*)hb;
    *(short8*)&Wlo[base] = *(short8*)lb;
    return;
  }

  int t = (blockIdx.x - 24) * 256 + tid;   // 0..1535
  int cl = t / 512;
  int idx = t - cl * 512;
  int part = idx >> 7, k = idx & 127;
  float val;
  if (part == 0) {            // S: Wo1 + WtoI_top @ (Wo2-Wo1)
    float s = Wout[k * 3 + cl];
    for (int f = 0; f < 128; f++)
      s = fmaf(WtoI[k * 128 + f],
               Wout[(128 + f) * 3 + cl] - Wout[f * 3 + cl], s);
    val = s;
  } else if (part == 1) {     // I: Wo2 + WtoR @ (Wo3-Wo2)
    float s = Wout[(128 + k) * 3 + cl];
    for (int f = 0; f < 128; f++)
      s = fmaf(WtoR[k * 128 + f],
               Wout[(256 + f) * 3 + cl] - Wout[(128 + f) * 3 + cl], s);
    val = s;
  } else if (part == 2) {     // R: Wo3
    val = Wout[(256 + k) * 3 + cl];
  } else {                    // NB: WtoI_bot @ (Wo2-Wo1)
    float s = 0.f;
    for (int f = 0; f < 128; f++)
      s = fmaf(WtoI[(128 + k) * 128 + f],
               Wout[(128 + f) * 3 + cl] - Wout[f * 3 + cl], s);
    val = s;
  }
  MT[cl * 512 + idx] = val;

  if (blockIdx.x == 24 && tid < 3) {
    float s = bout[tid];
    for (int f = 0; f < 128; f++) {
      s = fmaf(btoI[f], Wout[(128 + f) * 3 + tid] - Wout[f * 3 + tid], s);
      s = fmaf(btoR[f], Wout[(256 + f) * 3 + tid] - Wout[(128 + f) * 3 + tid], s);
    }
    cb[tid] = s;
  }
}

// ---------------------------------------------------------------------------
// K1a_store: GEMM P_w = feat @ (W_w+I) + b_w.  Emits column sum/sumsq stats
// AND stores P packed as split-bf16 (hi<<16 | lo) — one dword per element,
// coalesced.  Downstream reconstructs P = bf2f(hi)+bf2f(lo) (~2^-17 rel),
// eliminating the second GEMM entirely.
// ---------------------------------------------------------------------------
__global__ __launch_bounds__(512, 2) void k1a_store(
    const float* __restrict__ feat,
    const short* __restrict__ Whi, const short* __restrict__ Wlo,
    const float* __restrict__ bs, const float* __restrict__ bi,
    const float* __restrict__ br,
    float* __restrict__ stats,      // 6*128
    unsigned* __restrict__ Pp,      // 3*N*128 packed
    int N, int ntiles)
{
  __shared__ short Ah[2][64 * LDA];
  __shared__ short Al[2][64 * LDA];

  const int tid  = threadIdx.x;
  const int lane = tid & 63;
  const int wv   = tid >> 6;
  const int colb = wv * 16 + (lane & 15);
  const int kg   = lane >> 4;
  const int krow = kg * 8;

  const int sr = tid >> 3;
  const int so = tid & 7;

  const float bias[3] = {bs[colb], bi[colb], br[colb]};
  float ssum[3] = {0.f, 0.f, 0.f}, ssq[3] = {0.f, 0.f, 0.f};
  const size_t nf = (size_t)N * NFEAT;

  float4 pf[4];
  {
    int gr = blockIdx.x * 64 + sr; if (gr >= N) gr = N - 1;
    const float4* s4 = (const float4*)(feat + (size_t)gr * NFEAT + so * 16);
#pragma unroll
    for (int q = 0; q < 4; q++) pf[q] = s4[q];
    short hbuf[16], lbuf[16];
#pragma unroll
    for (int q = 0; q < 4; q++) {
      float xs[4] = {pf[q].x, pf[q].y, pf[q].z, pf[q].w};
#pragma unroll
      for (int cc = 0; cc < 4; cc++) {
        unsigned short h = f2bf(xs[cc]);
        hbuf[q * 4 + cc] = (short)h;
        lbuf[q * 4 + cc] = (short)f2bf(xs[cc] - bf2f(h));
      }
    }
    *(short8*)&Ah[0][sr * LDA + so * 16]     = *(short8*)(hbuf);
    *(short8*)&Ah[0][sr * LDA + so * 16 + 8] = *(short8*)(hbuf + 8);
    *(short8*)&Al[0][sr * LDA + so * 16]     = *(short8*)(lbuf);
    *(short8*)&Al[0][sr * LDA + so * 16 + 8] = *(short8*)(lbuf + 8);
  }
  __syncthreads();

  int cur = 0;
  for (int tile = blockIdx.x; tile < ntiles; tile += gridDim.x) {
    const int row0 = tile * 64;
    const int ntile = tile + gridDim.x;
    const bool have_next = ntile < ntiles;

    if (have_next) {
      int gr = ntile * 64 + sr; if (gr >= N) gr = N - 1;
      const float4* s4 = (const float4*)(feat + (size_t)gr * NFEAT + so * 16);
#pragma unroll
      for (int q = 0; q < 4; q++) pf[q] = s4[q];
    }

    const short* ah_c = &Ah[cur][0];
    const short* al_c = &Al[cur][0];

    f32x4 acc[3][4];
#pragma unroll
    for (int m = 0; m < 3; m++)
#pragma unroll
      for (int rf = 0; rf < 4; rf++)
        acc[m][rf] = (f32x4){0.f, 0.f, 0.f, 0.f};

#pragma unroll
    for (int kf = 0; kf < 4; kf++) {
      short8 bh[3], bl[3];
#pragma unroll
      for (int m = 0; m < 3; m++) {
        int fb = ((m * 16 + kf * 4 + kg) << 10) + (colb << 3);
        bh[m] = *(const short8*)&Whi[fb];
        bl[m] = *(const short8*)&Wlo[fb];
      }
      short8 ah[4], al[4];
#pragma unroll
      for (int rf = 0; rf < 4; rf++) {
        int off = (rf * 16 + (lane & 15)) * LDA + kf * 32 + krow;
        ah[rf] = *(const short8*)&ah_c[off];
        al[rf] = *(const short8*)&al_c[off];
      }
#pragma unroll
      for (int m = 0; m < 3; m++) {
#pragma unroll
        for (int rf = 0; rf < 4; rf++) {
          acc[m][rf] = __builtin_amdgcn_mfma_f32_16x16x32_bf16(
              ah[rf], bh[m], acc[m][rf], 0, 0, 0);
          acc[m][rf] = __builtin_amdgcn_mfma_f32_16x16x32_bf16(
              al[rf], bh[m], acc[m][rf], 0, 0, 0);
          acc[m][rf] = __builtin_amdgcn_mfma_f32_16x16x32_bf16(
              ah[rf], bl[m], acc[m][rf], 0, 0, 0);
        }
      }
    }

    // epilogue: stats + packed split-bf16 P store
#pragma unroll
    for (int rf = 0; rf < 4; rf++) {
      int lrb = rf * 16 + kg * 4;
#pragma unroll
      for (int g = 0; g < 4; g++) {
        int gr = row0 + lrb + g;
        bool ok = gr < N;
#pragma unroll
        for (int m = 0; m < 3; m++) {
          float v = acc[m][rf][g] + bias[m];
          if (ok) {
            ssum[m] += v;
            ssq[m]  += v * v;
            unsigned short h = f2bf(v);
            unsigned short l = f2bf(v - bf2f(h));
            Pp[(size_t)m * nf + (size_t)gr * NFEAT + colb] =
                ((unsigned)h << 16) | (unsigned)l;
          }
        }
      }
    }

    if (have_next) {
      short hbuf[16], lbuf[16];
#pragma unroll
      for (int q = 0; q < 4; q++) {
        float xs[4] = {pf[q].x, pf[q].y, pf[q].z, pf[q].w};
#pragma unroll
        for (int cc = 0; cc < 4; cc++) {
          unsigned short h = f2bf(xs[cc]);
          hbuf[q * 4 + cc] = (short)h;
          lbuf[q * 4 + cc] = (short)f2bf(xs[cc] - bf2f(h));
        }
      }
      int nb = cur ^ 1;
      *(short8*)&Ah[nb][sr * LDA + so * 16]     = *(short8*)(hbuf);
      *(short8*)&Ah[nb][sr * LDA + so * 16 + 8] = *(short8*)(hbuf + 8);
      *(short8*)&Al[nb][sr * LDA + so * 16]     = *(short8*)(lbuf);
      *(short8*)&Al[nb][sr * LDA + so * 16 + 8] = *(short8*)(lbuf + 8);
    }
    __syncthreads();
    cur ^= 1;
  }

#pragma unroll
  for (int m = 0; m < 3; m++) {
    float s = ssum[m], q = ssq[m];
    s += __shfl_xor(s, 16); s += __shfl_xor(s, 32);
    q += __shfl_xor(q, 16); q += __shfl_xor(q, 32);
    if (kg == 0) {
      unsafeAtomicAdd(&stats[m * 256 + colb], s);
      unsafeAtomicAdd(&stats[m * 256 + 128 + colb], q);
    }
  }
}

// ---------------------------------------------------------------------------
// K_bn: 1 block.  a = γ·rsqrt(var+ε);  kv = β − a·μ.   (bias already in P)
// ---------------------------------------------------------------------------
__global__ void k_bn(
    const float* __restrict__ stats,
    const float* __restrict__ gamma, const float* __restrict__ beta,
    float* __restrict__ av, float* __restrict__ kv, float invN)
{
  int t = threadIdx.x;
  if (t < 384) {
    int m = t >> 7, c = t & 127;
    float mu = stats[m * 256 + c] * invN;
    float var = stats[m * 256 + 128 + c] * invN - mu * mu;
    float a = gamma[c] * rsqrtf(var + EPSBN);
    av[t] = a;
    kv[t] = beta[c] - mu * a;
  }
}

// ---------------------------------------------------------------------------
// K1g: elementwise replacement for the second GEMM.  16 lanes/row; per m
// read 8 packed cols (uint4 x2, coalesced), v = relu(a·(Phi+Plo)+kv),
// fold into slog/q partials, shfl-reduce.  Also zeroes logit3R rows.
// NOTE: 256-thread block — ALL >256-element LDS staging must be strided
// loops (R17 bug: "if (tid<384)" left as_[256..383] uninitialized).
// ---------------------------------------------------------------------------
__global__ __launch_bounds__(256) void k1g_post(
    const unsigned* __restrict__ Pp,
    const float* __restrict__ av, const float* __restrict__ kv,
    const float* __restrict__ MT,
    float* __restrict__ slogA, float* __restrict__ qv,
    float* __restrict__ logit3R, int N, int N4, int nrt)
{
  __shared__ float MTs[1536];
  __shared__ float as_[384];
  __shared__ float kvs[384];
  const int tid = threadIdx.x;
  for (int i = tid; i < 1536; i += 256) MTs[i] = MT[i];
  for (int i = tid; i < 384; i += 256) { as_[i] = av[i]; kvs[i] = kv[i]; }
  __syncthreads();

  const int l15 = tid & 15;
  const int rg  = tid >> 4;
  const size_t nf = (size_t)N * NFEAT;

  for (int it = blockIdx.x; it < nrt; it += gridDim.x) {
    // zero logit3R for these 16 rows x NREP reps (128 float4; tid<128)
    if (tid < 128) {
      int rep = tid >> 4;
      int zr = it * 16 + (tid & 15);
      if (zr < N)
        *(float4*)&logit3R[(size_t)rep * N4 + (size_t)zr * 4] =
            make_float4(0.f, 0.f, 0.f, 0.f);
    }

    int row = it * 16 + rg;
    if (row >= N) continue;

    float s0 = 0.f, s1 = 0.f, s2 = 0.f;
    float q0 = 0.f, q1 = 0.f, q2 = 0.f;
#pragma unroll
    for (int m = 0; m < 3; m++) {
      const uint4* p4 =
          (const uint4*)(Pp + (size_t)m * nf + (size_t)row * NFEAT + l15 * 8);
      uint4 u0 = p4[0], u1 = p4[1];
      unsigned uu[8] = {u0.x, u0.y, u0.z, u0.w, u1.x, u1.y, u1.z, u1.w};
#pragma unroll
      for (int j = 0; j < 8; j++) {
        int c = l15 * 8 + j;
        float P = bf2f((unsigned short)(uu[j] >> 16)) +
                  bf2f((unsigned short)(uu[j] & 0xffffu));
        float v = fmaxf(fmaf(as_[m * 128 + c], P, kvs[m * 128 + c]), 0.f);
        s0 = fmaf(v, MTs[0 * 512 + m * 128 + c], s0);
        s1 = fmaf(v, MTs[1 * 512 + m * 128 + c], s1);
        s2 = fmaf(v, MTs[2 * 512 + m * 128 + c], s2);
        if (m == 1) {
          q0 = fmaf(v, MTs[0 * 512 + 384 + c], q0);
          q1 = fmaf(v, MTs[1 * 512 + 384 + c], q1);
          q2 = fmaf(v, MTs[2 * 512 + 384 + c], q2);
        }
      }
    }
#pragma unroll
    for (int off = 1; off < 16; off <<= 1) {
      s0 += __shfl_xor(s0, off); s1 += __shfl_xor(s1, off);
      s2 += __shfl_xor(s2, off);
      q0 += __shfl_xor(q0, off); q1 += __shfl_xor(q1, off);
      q2 += __shfl_xor(q2, off);
    }
    if (l15 == 0) {
      *(float4*)&slogA[(size_t)row * 4] = make_float4(s0, s1, s2, 0.f);
      *(float4*)&qv[(size_t)row * 4]    = make_float4(q0, q1, q2, 0.f);
    }
  }
}

// ---------------------------------------------------------------------------
// K_edge: 64 lanes = 21 edges x 3 comps; one atomic/lane, same-line merge,
// replica (waveID&7) spreads contention.
// ---------------------------------------------------------------------------
__global__ __launch_bounds__(256) void k_edge(
    const int* __restrict__ eidx, const float* __restrict__ ew,
    const float* __restrict__ q, float* __restrict__ logit3R,
    int E, int N4)
{
  const int wid  = (blockIdx.x * 256 + threadIdx.x) >> 6;
  const int lane = threadIdx.x & 63;
  const int el   = lane / 3;
  const int comp = lane - el * 3;
  if (el >= 21) return;
  const int e = wid * 21 + el;
  if (e >= E) return;

  int src = eidx[e];
  int dst = eidx[E + e];
  float w = ew[e];
  float qvv = q[(size_t)src * 4 + comp];
  int rep = wid & (NREP - 1);
  unsafeAtomicAdd(&logit3R[(size_t)rep * N4 + (size_t)dst * 4 + comp], qvv * w);
}

// ---------------------------------------------------------------------------
// K4t: out[r] = softmax(slog[r] + sum_rep logit3R[rep][r] + cb).
// ---------------------------------------------------------------------------
__global__ __launch_bounds__(256) void k4_final(
    const float* __restrict__ slogA, const float* __restrict__ logit3R,
    const float* __restrict__ cb,
    float* __restrict__ out, int N, int N4)
{
  int r = blockIdx.x * 256 + threadIdx.x;
  if (r >= N) return;
  float4 S = *(const float4*)&slogA[(size_t)r * 4];
  float l0 = S.x + cb[0], l1 = S.y + cb[1], l2 = S.z + cb[2];
#pragma unroll
  for (int rep = 0; rep < NREP; rep++) {
    float4 L = *(const float4*)&logit3R[(size_t)rep * N4 + (size_t)r * 4];
    l0 += L.x; l1 += L.y; l2 += L.z;
  }
  float mx = fmaxf(l0, fmaxf(l1, l2));
  float e0 = expf(l0 - mx), e1 = expf(l1 - mx), e2 = expf(l2 - mx);
  float inv = 1.f / (e0 + e1 + e2);
  out[(size_t)r * 3 + 0] = e0 * inv;
  out[(size_t)r * 3 + 1] = e1 * inv;
  out[(size_t)r * 3 + 2] = e2 * inv;
}

// ---------------------------------------------------------------------------
extern "C" void kernel_launch(void* const* d_in, const int* in_sizes, int n_in,
                              void* d_out, int out_size, void* d_ws, size_t ws_size,
                              hipStream_t stream)
{
  const float* feat  = (const float*)d_in[0];
  const int*   eidx  = (const int*)  d_in[1];
  const float* ew    = (const float*)d_in[2];
  const float* Ws    = (const float*)d_in[3];
  const float* bs    = (const float*)d_in[4];
  const float* Wi    = (const float*)d_in[5];
  const float* bi    = (const float*)d_in[6];
  const float* Wr    = (const float*)d_in[7];
  const float* br    = (const float*)d_in[8];
  const float* gamma = (const float*)d_in[9];
  const float* beta  = (const float*)d_in[10];
  const float* WtoI  = (const float*)d_in[11];
  const float* btoI  = (const float*)d_in[12];
  const float* WtoR  = (const float*)d_in[13];
  const float* btoR  = (const float*)d_in[14];
  const float* Wout  = (const float*)d_in[15];
  const float* bout  = (const float*)d_in[16];

  const int N = in_sizes[0] / NFEAT;
  const int E = in_sizes[2];
  const int N4 = 4 * N;
  const float invN = 1.0f / (float)N;
  float* out = (float*)d_out;

  float* logit3R = (float*)d_ws;                 // NREP*4*N
  float* slogA   = logit3R + (size_t)NREP * N4;  // 4*N
  float* qv      = slogA + 4 * (size_t)N;        // 4*N
  float* stats   = qv + 4 * (size_t)N;           // 768
  float* MT      = stats + 768;                  // 1536
  float* cb      = MT + 1536;                    // 4
  float* av      = cb + 4;                       // 384
  float* kv      = av + 384;                     // 384
  short* Whi     = (short*)(kv + 384);           // 49152
  short* Wlo     = Whi + 49152;                  // 49152
  unsigned* Pp   = (unsigned*)(Wlo + 49152);     // 3*N*128

  hipMemsetAsync(stats, 0, 768 * sizeof(float), stream);

  const int nt = (N + 63) / 64;           // 1563
  const int g1 = (nt + 2) / 3;            // 521
  const int nrt = (N + 15) / 16;          // 6250

  kp_params<<<30, 256, 0, stream>>>(Ws, Wi, Wr, WtoI, btoI, WtoR, btoR,
                                    Wout, bout, Whi, Wlo, MT, cb);
  k1a_store<<<g1, 512, 0, stream>>>(feat, Whi, Wlo, bs, bi, br, stats, Pp,
                                    N, nt);
  k_bn<<<1, 384, 0, stream>>>(stats, gamma, beta, av, kv, invN);
  k1g_post<<<2048, 256, 0, stream>>>(Pp, av, kv, MT, slogA, qv, logit3R,
                                     N, N4, nrt);
  const int nwaves = (E + 20) / 21;
  k_edge<<<(nwaves + 3) / 4, 256, 0, stream>>>(eidx, ew, qv, logit3R, E, N4);
  k4_final<<<(N + 255) / 256, 256, 0, stream>>>(slogA, logit3R, cb, out, N, N4);
}

// Round 19
// 161.822 us; speedup vs baseline: 1.6679x; 1.0399x over previous
//
#include <hip/hip_runtime.h>
#include <math.h>

#define NFEAT 128
#define EPSBN 1e-5f
#define LDA 136   // bf16 elems per LDS row: 128 + 8 pad
#define NREP 8    // logit3 replicas to spread atomic contention

typedef __attribute__((ext_vector_type(8))) short short8;
typedef __attribute__((ext_vector_type(4))) float f32x4;

__device__ __forceinline__ unsigned short f2bf(float x) {
  union { float f; unsigned u; } v; v.f = x;
  unsigned r = v.u + 0x7FFF + ((v.u >> 16) & 1);   // RNE
  return (unsigned short)(r >> 16);
}
__device__ __forceinline__ float bf2f(unsigned short h) {
  union { unsigned u; float f; } v; v.u = (unsigned)h << 16;
  return v.f;
}

// ---------------------------------------------------------------------------
// KP: blocks 0..23: split W' = (W + I) into bf16 hi/lo planes in MFMA
// B-fragment order.  Blocks 24..29: fold back-half into MT + cb.
//   logits = S@M1 + I@M3 + R@M4 + NB@M2 + cb
// MT layout: MT[cl*512 + part*128 + k], part: 0=S 1=I 2=R 3=NB.
// ---------------------------------------------------------------------------
__global__ __launch_bounds__(256) void kp_params(
    const float* __restrict__ Ws, const float* __restrict__ Wi,
    const float* __restrict__ Wr,
    const float* __restrict__ WtoI, const float* __restrict__ btoI,
    const float* __restrict__ WtoR, const float* __restrict__ btoR,
    const float* __restrict__ Wout, const float* __restrict__ bout,
    short* __restrict__ Whi, short* __restrict__ Wlo,
    float* __restrict__ MT, float* __restrict__ cb)
{
  const int tid = threadIdx.x;
  if (blockIdx.x < 24) {
    int t = blockIdx.x * 256 + tid;   // 6144 total
    int m   = t >> 11;
    int rem = t & 2047;
    int kf  = rem >> 9;
    int kg  = (rem >> 7) & 3;
    int c   = rem & 127;
    const float* W = (m == 0) ? Ws : ((m == 1) ? Wi : Wr);
    short hb[8], lb[8];
#pragma unroll
    for (int j = 0; j < 8; j++) {
      int k = kf * 32 + kg * 8 + j;
      float w = W[(size_t)k * NFEAT + c] + (k == c ? 1.0f : 0.0f);
      unsigned short h = f2bf(w);
      hb[j] = (short)h;
      lb[j] = (short)f2bf(w - bf2f(h));
    }
    int base = ((m * 16 + kf * 4 + kg) << 10) + (c << 3);
    *(short8*)&Whi[base] = *(short8*)hb;
    *(short8*)&Wlo[base] = *(short8*)lb;
    return;
  }

  int t = (blockIdx.x - 24) * 256 + tid;   // 0..1535
  int cl = t / 512;
  int idx = t - cl * 512;
  int part = idx >> 7, k = idx & 127;
  float val;
  if (part == 0) {            // S: Wo1 + WtoI_top @ (Wo2-Wo1)
    float s = Wout[k * 3 + cl];
    for (int f = 0; f < 128; f++)
      s = fmaf(WtoI[k * 128 + f],
               Wout[(128 + f) * 3 + cl] - Wout[f * 3 + cl], s);
    val = s;
  } else if (part == 1) {     // I: Wo2 + WtoR @ (Wo3-Wo2)
    float s = Wout[(128 + k) * 3 + cl];
    for (int f = 0; f < 128; f++)
      s = fmaf(WtoR[k * 128 + f],
               Wout[(256 + f) * 3 + cl] - Wout[(128 + f) * 3 + cl], s);
    val = s;
  } else if (part == 2) {     // R: Wo3
    val = Wout[(256 + k) * 3 + cl];
  } else {                    // NB: WtoI_bot @ (Wo2-Wo1)
    float s = 0.f;
    for (int f = 0; f < 128; f++)
      s = fmaf(WtoI[(128 + k) * 128 + f],
               Wout[(128 + f) * 3 + cl] - Wout[f * 3 + cl], s);
    val = s;
  }
  MT[cl * 512 + idx] = val;

  if (blockIdx.x == 24 && tid < 3) {
    float s = bout[tid];
    for (int f = 0; f < 128; f++) {
      s = fmaf(btoI[f], Wout[(128 + f) * 3 + tid] - Wout[f * 3 + tid], s);
      s = fmaf(btoR[f], Wout[(256 + f) * 3 + tid] - Wout[(128 + f) * 3 + tid], s);
    }
    cb[tid] = s;
  }
}

// ---------------------------------------------------------------------------
// K1a_store: GEMM P_w = feat @ (W_w+I) + b_w.  Emits column sum/sumsq stats
// AND stores P packed as split-bf16 (hi<<16 | lo).  Loop barrier is raw
// s_barrier + lgkmcnt(0) only — __syncthreads would drain vmcnt(0), which
// serialized ~26 us of P-store wire time per dispatch (R18 counters).
// ---------------------------------------------------------------------------
__global__ __launch_bounds__(512, 2) void k1a_store(
    const float* __restrict__ feat,
    const short* __restrict__ Whi, const short* __restrict__ Wlo,
    const float* __restrict__ bs, const float* __restrict__ bi,
    const float* __restrict__ br,
    float* __restrict__ stats,      // 6*128
    unsigned* __restrict__ Pp,      // 3*N*128 packed
    int N, int ntiles)
{
  __shared__ short Ah[2][64 * LDA];
  __shared__ short Al[2][64 * LDA];

  const int tid  = threadIdx.x;
  const int lane = tid & 63;
  const int wv   = tid >> 6;
  const int colb = wv * 16 + (lane & 15);
  const int kg   = lane >> 4;
  const int krow = kg * 8;

  const int sr = tid >> 3;
  const int so = tid & 7;

  const float bias[3] = {bs[colb], bi[colb], br[colb]};
  float ssum[3] = {0.f, 0.f, 0.f}, ssq[3] = {0.f, 0.f, 0.f};
  const size_t nf = (size_t)N * NFEAT;

  float4 pf[4];
  {
    int gr = blockIdx.x * 64 + sr; if (gr >= N) gr = N - 1;
    const float4* s4 = (const float4*)(feat + (size_t)gr * NFEAT + so * 16);
#pragma unroll
    for (int q = 0; q < 4; q++) pf[q] = s4[q];
    short hbuf[16], lbuf[16];
#pragma unroll
    for (int q = 0; q < 4; q++) {
      float xs[4] = {pf[q].x, pf[q].y, pf[q].z, pf[q].w};
#pragma unroll
      for (int cc = 0; cc < 4; cc++) {
        unsigned short h = f2bf(xs[cc]);
        hbuf[q * 4 + cc] = (short)h;
        lbuf[q * 4 + cc] = (short)f2bf(xs[cc] - bf2f(h));
      }
    }
    *(short8*)&Ah[0][sr * LDA + so * 16]     = *(short8*)(hbuf);
    *(short8*)&Ah[0][sr * LDA + so * 16 + 8] = *(short8*)(hbuf + 8);
    *(short8*)&Al[0][sr * LDA + so * 16]     = *(short8*)(lbuf);
    *(short8*)&Al[0][sr * LDA + so * 16 + 8] = *(short8*)(lbuf + 8);
  }
  __syncthreads();

  int cur = 0;
  for (int tile = blockIdx.x; tile < ntiles; tile += gridDim.x) {
    const int row0 = tile * 64;
    const int ntile = tile + gridDim.x;
    const bool have_next = ntile < ntiles;

    if (have_next) {
      int gr = ntile * 64 + sr; if (gr >= N) gr = N - 1;
      const float4* s4 = (const float4*)(feat + (size_t)gr * NFEAT + so * 16);
#pragma unroll
      for (int q = 0; q < 4; q++) pf[q] = s4[q];
    }

    const short* ah_c = &Ah[cur][0];
    const short* al_c = &Al[cur][0];

    f32x4 acc[3][4];
#pragma unroll
    for (int m = 0; m < 3; m++)
#pragma unroll
      for (int rf = 0; rf < 4; rf++)
        acc[m][rf] = (f32x4){0.f, 0.f, 0.f, 0.f};

#pragma unroll
    for (int kf = 0; kf < 4; kf++) {
      short8 bh[3], bl[3];
#pragma unroll
      for (int m = 0; m < 3; m++) {
        int fb = ((m * 16 + kf * 4 + kg) << 10) + (colb << 3);
        bh[m] = *(const short8*)&Whi[fb];
        bl[m] = *(const short8*)&Wlo[fb];
      }
      short8 ah[4], al[4];
#pragma unroll
      for (int rf = 0; rf < 4; rf++) {
        int off = (rf * 16 + (lane & 15)) * LDA + kf * 32 + krow;
        ah[rf] = *(const short8*)&ah_c[off];
        al[rf] = *(const short8*)&al_c[off];
      }
#pragma unroll
      for (int m = 0; m < 3; m++) {
#pragma unroll
        for (int rf = 0; rf < 4; rf++) {
          acc[m][rf] = __builtin_amdgcn_mfma_f32_16x16x32_bf16(
              ah[rf], bh[m], acc[m][rf], 0, 0, 0);
          acc[m][rf] = __builtin_amdgcn_mfma_f32_16x16x32_bf16(
              al[rf], bh[m], acc[m][rf], 0, 0, 0);
          acc[m][rf] = __builtin_amdgcn_mfma_f32_16x16x32_bf16(
              ah[rf], bl[m], acc[m][rf], 0, 0, 0);
        }
      }
    }

    // epilogue: stats + packed split-bf16 P store (fire-and-forget)
#pragma unroll
    for (int rf = 0; rf < 4; rf++) {
      int lrb = rf * 16 + kg * 4;
#pragma unroll
      for (int g = 0; g < 4; g++) {
        int gr = row0 + lrb + g;
        bool ok = gr < N;
#pragma unroll
        for (int m = 0; m < 3; m++) {
          float v = acc[m][rf][g] + bias[m];
          if (ok) {
            ssum[m] += v;
            ssq[m]  += v * v;
            unsigned short h = f2bf(v);
            unsigned short l = f2bf(v - bf2f(h));
            Pp[(size_t)m * nf + (size_t)gr * NFEAT + colb] =
                ((unsigned)h << 16) | (unsigned)l;
          }
        }
      }
    }

    if (have_next) {
      short hbuf[16], lbuf[16];
#pragma unroll
      for (int q = 0; q < 4; q++) {
        float xs[4] = {pf[q].x, pf[q].y, pf[q].z, pf[q].w};
#pragma unroll
        for (int cc = 0; cc < 4; cc++) {
          unsigned short h = f2bf(xs[cc]);
          hbuf[q * 4 + cc] = (short)h;
          lbuf[q * 4 + cc] = (short)f2bf(xs[cc] - bf2f(h));
        }
      }
      int nb = cur ^ 1;
      *(short8*)&Ah[nb][sr * LDA + so * 16]     = *(short8*)(hbuf);
      *(short8*)&Ah[nb][sr * LDA + so * 16 + 8] = *(short8*)(hbuf + 8);
      *(short8*)&Al[nb][sr * LDA + so * 16]     = *(short8*)(lbuf);
      *(short8*)&Al[nb][sr * LDA + so * 16 + 8] = *(short8*)(lbuf + 8);
    }
    // barrier WITHOUT vmcnt drain: ds_writes drained (lgkmcnt), global
    // P-stores stay in flight across tiles.
    asm volatile("s_waitcnt lgkmcnt(0)" ::: "memory");
    __builtin_amdgcn_s_barrier();
    cur ^= 1;
  }

#pragma unroll
  for (int m = 0; m < 3; m++) {
    float s = ssum[m], q = ssq[m];
    s += __shfl_xor(s, 16); s += __shfl_xor(s, 32);
    q += __shfl_xor(q, 16); q += __shfl_xor(q, 32);
    if (kg == 0) {
      unsafeAtomicAdd(&stats[m * 256 + colb], s);
      unsafeAtomicAdd(&stats[m * 256 + 128 + colb], q);
    }
  }
}

// ---------------------------------------------------------------------------
// K_bn: 1 block.  Builds packed epilogue tables at swizzled index
// idx = m*128 + (c&7)*16 + (c>>3):
//   A4[idx] = {MT1[m,c], MT2[m,c], MT3[m,c], a}
//   B4[idx] = {MTq1[c], MTq2[c], MTq3[c], kv}   (q-parts zero for m != 1)
// a = gamma*rsqrt(var+eps); kv = beta - a*mu.
// ---------------------------------------------------------------------------
__global__ void k_bn(
    const float* __restrict__ stats,
    const float* __restrict__ gamma, const float* __restrict__ beta,
    const float* __restrict__ MT,
    float4* __restrict__ A4, float4* __restrict__ B4, float invN)
{
  int t = threadIdx.x;
  if (t < 384) {
    int m = t >> 7, c = t & 127;
    float mu = stats[m * 256 + c] * invN;
    float var = stats[m * 256 + 128 + c] * invN - mu * mu;
    float a = gamma[c] * rsqrtf(var + EPSBN);
    float kv = beta[c] - mu * a;
    int idx = m * 128 + (c & 7) * 16 + (c >> 3);
    A4[idx] = make_float4(MT[0 * 512 + m * 128 + c],
                          MT[1 * 512 + m * 128 + c],
                          MT[2 * 512 + m * 128 + c], a);
    if (m == 1)
      B4[idx] = make_float4(MT[0 * 512 + 384 + c],
                            MT[1 * 512 + 384 + c],
                            MT[2 * 512 + 384 + c], kv);
    else
      B4[idx] = make_float4(0.f, 0.f, 0.f, kv);
  }
}

// ---------------------------------------------------------------------------
// K1g: elementwise replacement for the second GEMM.  16 lanes/row; per m
// read 8 packed cols (uint4 x2, coalesced); per (m,j) TWO conflict-free
// b128 LDS reads (A4s/B4s swizzled) give {mt0..2, a} and {mq0..2, kv};
// v = relu(a*(Phi+Plo)+kv); branchless q-accum (B4.xyz zero for m != 1).
// Also zeroes logit3R rows.  256-thr block: >256 LDS staging MUST be
// strided loops (R17 lesson).
// ---------------------------------------------------------------------------
__global__ __launch_bounds__(256) void k1g_post(
    const unsigned* __restrict__ Pp,
    const float4* __restrict__ A4, const float4* __restrict__ B4,
    float* __restrict__ slogA, float* __restrict__ qv,
    float* __restrict__ logit3R, int N, int N4, int nrt)
{
  __shared__ float4 A4s[384];
  __shared__ float4 B4s[384];
  const int tid = threadIdx.x;
  for (int i = tid; i < 384; i += 256) { A4s[i] = A4[i]; B4s[i] = B4[i]; }
  __syncthreads();

  const int l15 = tid & 15;
  const int rg  = tid >> 4;
  const size_t nf = (size_t)N * NFEAT;

  for (int it = blockIdx.x; it < nrt; it += gridDim.x) {
    // zero logit3R for these 16 rows x NREP reps (128 float4; tid<128)
    if (tid < 128) {
      int rep = tid >> 4;
      int zr = it * 16 + (tid & 15);
      if (zr < N)
        *(float4*)&logit3R[(size_t)rep * N4 + (size_t)zr * 4] =
            make_float4(0.f, 0.f, 0.f, 0.f);
    }

    int row = it * 16 + rg;
    if (row >= N) continue;

    float s0 = 0.f, s1 = 0.f, s2 = 0.f;
    float q0 = 0.f, q1 = 0.f, q2 = 0.f;
#pragma unroll
    for (int m = 0; m < 3; m++) {
      const uint4* p4 =
          (const uint4*)(Pp + (size_t)m * nf + (size_t)row * NFEAT + l15 * 8);
      uint4 u0 = p4[0], u1 = p4[1];
      unsigned uu[8] = {u0.x, u0.y, u0.z, u0.w, u1.x, u1.y, u1.z, u1.w};
#pragma unroll
      for (int j = 0; j < 8; j++) {
        float4 ab = A4s[m * 128 + j * 16 + l15];
        float4 bq = B4s[m * 128 + j * 16 + l15];
        float P = bf2f((unsigned short)(uu[j] >> 16)) +
                  bf2f((unsigned short)(uu[j] & 0xffffu));
        float v = fmaxf(fmaf(ab.w, P, bq.w), 0.f);
        s0 = fmaf(v, ab.x, s0);
        s1 = fmaf(v, ab.y, s1);
        s2 = fmaf(v, ab.z, s2);
        q0 = fmaf(v, bq.x, q0);
        q1 = fmaf(v, bq.y, q1);
        q2 = fmaf(v, bq.z, q2);
      }
    }
#pragma unroll
    for (int off = 1; off < 16; off <<= 1) {
      s0 += __shfl_xor(s0, off); s1 += __shfl_xor(s1, off);
      s2 += __shfl_xor(s2, off);
      q0 += __shfl_xor(q0, off); q1 += __shfl_xor(q1, off);
      q2 += __shfl_xor(q2, off);
    }
    if (l15 == 0) {
      *(float4*)&slogA[(size_t)row * 4] = make_float4(s0, s1, s2, 0.f);
      *(float4*)&qv[(size_t)row * 4]    = make_float4(q0, q1, q2, 0.f);
    }
  }
}

// ---------------------------------------------------------------------------
// K_edge: 64 lanes = 21 edges x 3 comps; one atomic/lane, same-line merge,
// replica (waveID&7) spreads contention.
// ---------------------------------------------------------------------------
__global__ __launch_bounds__(256) void k_edge(
    const int* __restrict__ eidx, const float* __restrict__ ew,
    const float* __restrict__ q, float* __restrict__ logit3R,
    int E, int N4)
{
  const int wid  = (blockIdx.x * 256 + threadIdx.x) >> 6;
  const int lane = threadIdx.x & 63;
  const int el   = lane / 3;
  const int comp = lane - el * 3;
  if (el >= 21) return;
  const int e = wid * 21 + el;
  if (e >= E) return;

  int src = eidx[e];
  int dst = eidx[E + e];
  float w = ew[e];
  float qvv = q[(size_t)src * 4 + comp];
  int rep = wid & (NREP - 1);
  unsafeAtomicAdd(&logit3R[(size_t)rep * N4 + (size_t)dst * 4 + comp], qvv * w);
}

// ---------------------------------------------------------------------------
// K4t: out[r] = softmax(slog[r] + sum_rep logit3R[rep][r] + cb).
// ---------------------------------------------------------------------------
__global__ __launch_bounds__(256) void k4_final(
    const float* __restrict__ slogA, const float* __restrict__ logit3R,
    const float* __restrict__ cb,
    float* __restrict__ out, int N, int N4)
{
  int r = blockIdx.x * 256 + threadIdx.x;
  if (r >= N) return;
  float4 S = *(const float4*)&slogA[(size_t)r * 4];
  float l0 = S.x + cb[0], l1 = S.y + cb[1], l2 = S.z + cb[2];
#pragma unroll
  for (int rep = 0; rep < NREP; rep++) {
    float4 L = *(const float4*)&logit3R[(size_t)rep * N4 + (size_t)r * 4];
    l0 += L.x; l1 += L.y; l2 += L.z;
  }
  float mx = fmaxf(l0, fmaxf(l1, l2));
  float e0 = expf(l0 - mx), e1 = expf(l1 - mx), e2 = expf(l2 - mx);
  float inv = 1.f / (e0 + e1 + e2);
  out[(size_t)r * 3 + 0] = e0 * inv;
  out[(size_t)r * 3 + 1] = e1 * inv;
  out[(size_t)r * 3 + 2] = e2 * inv;
}

// ---------------------------------------------------------------------------
extern "C" void kernel_launch(void* const* d_in, const int* in_sizes, int n_in,
                              void* d_out, int out_size, void* d_ws, size_t ws_size,
                              hipStream_t stream)
{
  const float* feat  = (const float*)d_in[0];
  const int*   eidx  = (const int*)  d_in[1];
  const float* ew    = (const float*)d_in[2];
  const float* Ws    = (const float*)d_in[3];
  const float* bs    = (const float*)d_in[4];
  const float* Wi    = (const float*)d_in[5];
  const float* bi    = (const float*)d_in[6];
  const float* Wr    = (const float*)d_in[7];
  const float* br    = (const float*)d_in[8];
  const float* gamma = (const float*)d_in[9];
  const float* beta  = (const float*)d_in[10];
  const float* WtoI  = (const float*)d_in[11];
  const float* btoI  = (const float*)d_in[12];
  const float* WtoR  = (const float*)d_in[13];
  const float* btoR  = (const float*)d_in[14];
  const float* Wout  = (const float*)d_in[15];
  const float* bout  = (const float*)d_in[16];

  const int N = in_sizes[0] / NFEAT;
  const int E = in_sizes[2];
  const int N4 = 4 * N;
  const float invN = 1.0f / (float)N;
  float* out = (float*)d_out;

  float* logit3R = (float*)d_ws;                 // NREP*4*N
  float* slogA   = logit3R + (size_t)NREP * N4;  // 4*N
  float* qv      = slogA + 4 * (size_t)N;        // 4*N
  float* stats   = qv + 4 * (size_t)N;           // 768
  float* MT      = stats + 768;                  // 1536
  float* cb      = MT + 1536;                    // 4
  float4* A4     = (float4*)(cb + 4);            // 384 float4
  float4* B4     = A4 + 384;                     // 384 float4
  short* Whi     = (short*)(B4 + 384);           // 49152
  short* Wlo     = Whi + 49152;                  // 49152
  unsigned* Pp   = (unsigned*)(Wlo + 49152);     // 3*N*128

  hipMemsetAsync(stats, 0, 768 * sizeof(float), stream);

  const int nt = (N + 63) / 64;           // 1563
  const int g1 = (nt + 2) / 3;            // 521
  const int nrt = (N + 15) / 16;          // 6250

  kp_params<<<30, 256, 0, stream>>>(Ws, Wi, Wr, WtoI, btoI, WtoR, btoR,
                                    Wout, bout, Whi, Wlo, MT, cb);
  k1a_store<<<g1, 512, 0, stream>>>(feat, Whi, Wlo, bs, bi, br, stats, Pp,
                                    N, nt);
  k_bn<<<1, 384, 0, stream>>>(stats, gamma, beta, MT, A4, B4, invN);
  k1g_post<<<2048, 256, 0, stream>>>(Pp, A4, B4, slogA, qv, logit3R,
                                     N, N4, nrt);
  const int nwaves = (E + 20) / 21;
  k_edge<<<(nwaves + 3) / 4, 256, 0, stream>>>(eidx, ew, qv, logit3R, E, N4);
  k4_final<<<(N + 255) / 256, 256, 0, stream>>>(slogA, logit3R, cb, out, N, N4);
}

// Round 20
// 147.858 us; speedup vs baseline: 1.8254x; 1.0944x over previous
//
#include <hip/hip_runtime.h>
#include <math.h>

#define NFEAT 128
#define EPSBN 1e-5f
#define LDA 136   // bf16 elems per LDS row: 128 + 8 pad
#define NREP 8    // logit3 replicas to spread atomic contention

typedef __attribute__((ext_vector_type(8))) short short8;
typedef __attribute__((ext_vector_type(4))) float f32x4;

__device__ __forceinline__ unsigned short f2bf(float x) {
  union { float f; unsigned u; } v; v.f = x;
  unsigned r = v.u + 0x7FFF + ((v.u >> 16) & 1);   // RNE
  return (unsigned short)(r >> 16);
}
__device__ __forceinline__ float bf2f(unsigned short h) {
  union { unsigned u; float f; } v; v.u = (unsigned)h << 16;
  return v.f;
}

// ---------------------------------------------------------------------------
// KP: blocks 0..23: split W' = (W + I) into bf16 hi/lo planes in MFMA
// B-fragment order.  Blocks 24..29: fold back-half into MT + cb.
//   logits = S@M1 + I@M3 + R@M4 + NB@M2 + cb
// MT layout: MT[cl*512 + part*128 + k], part: 0=S 1=I 2=R 3=NB.
// ---------------------------------------------------------------------------
__global__ __launch_bounds__(256) void kp_params(
    const float* __restrict__ Ws, const float* __restrict__ Wi,
    const float* __restrict__ Wr,
    const float* __restrict__ WtoI, const float* __restrict__ btoI,
    const float* __restrict__ WtoR, const float* __restrict__ btoR,
    const float* __restrict__ Wout, const float* __restrict__ bout,
    short* __restrict__ Whi, short* __restrict__ Wlo,
    float* __restrict__ MT, float* __restrict__ cb)
{
  const int tid = threadIdx.x;
  if (blockIdx.x < 24) {
    int t = blockIdx.x * 256 + tid;   // 6144 total
    int m   = t >> 11;
    int rem = t & 2047;
    int kf  = rem >> 9;
    int kg  = (rem >> 7) & 3;
    int c   = rem & 127;
    const float* W = (m == 0) ? Ws : ((m == 1) ? Wi : Wr);
    short hb[8], lb[8];
#pragma unroll
    for (int j = 0; j < 8; j++) {
      int k = kf * 32 + kg * 8 + j;
      float w = W[(size_t)k * NFEAT + c] + (k == c ? 1.0f : 0.0f);
      unsigned short h = f2bf(w);
      hb[j] = (short)h;
      lb[j] = (short)f2bf(w - bf2f(h));
    }
    int base = ((m * 16 + kf * 4 + kg) << 10) + (c << 3);
    *(short8*)&Whi[base] = *(short8*)hb;
    *(short8*)&Wlo[base] = *(short8*)lb;
    return;
  }

  int t = (blockIdx.x - 24) * 256 + tid;   // 0..1535
  int cl = t / 512;
  int idx = t - cl * 512;
  int part = idx >> 7, k = idx & 127;
  float val;
  if (part == 0) {            // S: Wo1 + WtoI_top @ (Wo2-Wo1)
    float s = Wout[k * 3 + cl];
    for (int f = 0; f < 128; f++)
      s = fmaf(WtoI[k * 128 + f],
               Wout[(128 + f) * 3 + cl] - Wout[f * 3 + cl], s);
    val = s;
  } else if (part == 1) {     // I: Wo2 + WtoR @ (Wo3-Wo2)
    float s = Wout[(128 + k) * 3 + cl];
    for (int f = 0; f < 128; f++)
      s = fmaf(WtoR[k * 128 + f],
               Wout[(256 + f) * 3 + cl] - Wout[(128 + f) * 3 + cl], s);
    val = s;
  } else if (part == 2) {     // R: Wo3
    val = Wout[(256 + k) * 3 + cl];
  } else {                    // NB: WtoI_bot @ (Wo2-Wo1)
    float s = 0.f;
    for (int f = 0; f < 128; f++)
      s = fmaf(WtoI[(128 + k) * 128 + f],
               Wout[(128 + f) * 3 + cl] - Wout[f * 3 + cl], s);
    val = s;
  }
  MT[cl * 512 + idx] = val;

  if (blockIdx.x == 24 && tid < 3) {
    float s = bout[tid];
    for (int f = 0; f < 128; f++) {
      s = fmaf(btoI[f], Wout[(128 + f) * 3 + tid] - Wout[f * 3 + tid], s);
      s = fmaf(btoR[f], Wout[(256 + f) * 3 + tid] - Wout[(128 + f) * 3 + tid], s);
    }
    cb[tid] = s;
  }
}

// ---------------------------------------------------------------------------
// K1a_store: GEMM P_w = feat @ (W_w+I) + b_w.  Emits column sum/sumsq stats
// (fp32-exact, BEFORE quantization) and stores P as SINGLE bf16 (ushort) —
// halves write traffic vs split-pair (R19: 154 MB wire + split-conversion
// VALU were both on the critical path).  Downstream BN absorbs the ~2^-9
// P-quantization (est. +2e-3..4e-3 softmax absmax, threshold 2e-2).
// ---------------------------------------------------------------------------
__global__ __launch_bounds__(512, 2) void k1a_store(
    const float* __restrict__ feat,
    const short* __restrict__ Whi, const short* __restrict__ Wlo,
    const float* __restrict__ bs, const float* __restrict__ bi,
    const float* __restrict__ br,
    float* __restrict__ stats,           // 6*128
    unsigned short* __restrict__ Pb,     // 3*N*128 bf16
    int N, int ntiles)
{
  __shared__ short Ah[2][64 * LDA];
  __shared__ short Al[2][64 * LDA];

  const int tid  = threadIdx.x;
  const int lane = tid & 63;
  const int wv   = tid >> 6;
  const int colb = wv * 16 + (lane & 15);
  const int kg   = lane >> 4;
  const int krow = kg * 8;

  const int sr = tid >> 3;
  const int so = tid & 7;

  const float bias[3] = {bs[colb], bi[colb], br[colb]};
  float ssum[3] = {0.f, 0.f, 0.f}, ssq[3] = {0.f, 0.f, 0.f};
  const size_t nf = (size_t)N * NFEAT;

  float4 pf[4];
  {
    int gr = blockIdx.x * 64 + sr; if (gr >= N) gr = N - 1;
    const float4* s4 = (const float4*)(feat + (size_t)gr * NFEAT + so * 16);
#pragma unroll
    for (int q = 0; q < 4; q++) pf[q] = s4[q];
    short hbuf[16], lbuf[16];
#pragma unroll
    for (int q = 0; q < 4; q++) {
      float xs[4] = {pf[q].x, pf[q].y, pf[q].z, pf[q].w};
#pragma unroll
      for (int cc = 0; cc < 4; cc++) {
        unsigned short h = f2bf(xs[cc]);
        hbuf[q * 4 + cc] = (short)h;
        lbuf[q * 4 + cc] = (short)f2bf(xs[cc] - bf2f(h));
      }
    }
    *(short8*)&Ah[0][sr * LDA + so * 16]     = *(short8*)(hbuf);
    *(short8*)&Ah[0][sr * LDA + so * 16 + 8] = *(short8*)(hbuf + 8);
    *(short8*)&Al[0][sr * LDA + so * 16]     = *(short8*)(lbuf);
    *(short8*)&Al[0][sr * LDA + so * 16 + 8] = *(short8*)(lbuf + 8);
  }
  __syncthreads();

  int cur = 0;
  for (int tile = blockIdx.x; tile < ntiles; tile += gridDim.x) {
    const int row0 = tile * 64;
    const int ntile = tile + gridDim.x;
    const bool have_next = ntile < ntiles;

    if (have_next) {
      int gr = ntile * 64 + sr; if (gr >= N) gr = N - 1;
      const float4* s4 = (const float4*)(feat + (size_t)gr * NFEAT + so * 16);
#pragma unroll
      for (int q = 0; q < 4; q++) pf[q] = s4[q];
    }

    const short* ah_c = &Ah[cur][0];
    const short* al_c = &Al[cur][0];

    f32x4 acc[3][4];
#pragma unroll
    for (int m = 0; m < 3; m++)
#pragma unroll
      for (int rf = 0; rf < 4; rf++)
        acc[m][rf] = (f32x4){0.f, 0.f, 0.f, 0.f};

#pragma unroll
    for (int kf = 0; kf < 4; kf++) {
      short8 bh[3], bl[3];
#pragma unroll
      for (int m = 0; m < 3; m++) {
        int fb = ((m * 16 + kf * 4 + kg) << 10) + (colb << 3);
        bh[m] = *(const short8*)&Whi[fb];
        bl[m] = *(const short8*)&Wlo[fb];
      }
      short8 ah[4], al[4];
#pragma unroll
      for (int rf = 0; rf < 4; rf++) {
        int off = (rf * 16 + (lane & 15)) * LDA + kf * 32 + krow;
        ah[rf] = *(const short8*)&ah_c[off];
        al[rf] = *(const short8*)&al_c[off];
      }
#pragma unroll
      for (int m = 0; m < 3; m++) {
#pragma unroll
        for (int rf = 0; rf < 4; rf++) {
          acc[m][rf] = __builtin_amdgcn_mfma_f32_16x16x32_bf16(
              ah[rf], bh[m], acc[m][rf], 0, 0, 0);
          acc[m][rf] = __builtin_amdgcn_mfma_f32_16x16x32_bf16(
              al[rf], bh[m], acc[m][rf], 0, 0, 0);
          acc[m][rf] = __builtin_amdgcn_mfma_f32_16x16x32_bf16(
              ah[rf], bl[m], acc[m][rf], 0, 0, 0);
        }
      }
    }

    // epilogue: fp32 stats + single-bf16 P store (fire-and-forget)
#pragma unroll
    for (int rf = 0; rf < 4; rf++) {
      int lrb = rf * 16 + kg * 4;
#pragma unroll
      for (int g = 0; g < 4; g++) {
        int gr = row0 + lrb + g;
        bool ok = gr < N;
#pragma unroll
        for (int m = 0; m < 3; m++) {
          float v = acc[m][rf][g] + bias[m];
          if (ok) {
            ssum[m] += v;
            ssq[m]  += v * v;
            Pb[(size_t)m * nf + (size_t)gr * NFEAT + colb] = f2bf(v);
          }
        }
      }
    }

    if (have_next) {
      short hbuf[16], lbuf[16];
#pragma unroll
      for (int q = 0; q < 4; q++) {
        float xs[4] = {pf[q].x, pf[q].y, pf[q].z, pf[q].w};
#pragma unroll
        for (int cc = 0; cc < 4; cc++) {
          unsigned short h = f2bf(xs[cc]);
          hbuf[q * 4 + cc] = (short)h;
          lbuf[q * 4 + cc] = (short)f2bf(xs[cc] - bf2f(h));
        }
      }
      int nb = cur ^ 1;
      *(short8*)&Ah[nb][sr * LDA + so * 16]     = *(short8*)(hbuf);
      *(short8*)&Ah[nb][sr * LDA + so * 16 + 8] = *(short8*)(hbuf + 8);
      *(short8*)&Al[nb][sr * LDA + so * 16]     = *(short8*)(lbuf);
      *(short8*)&Al[nb][sr * LDA + so * 16 + 8] = *(short8*)(lbuf + 8);
    }
    // barrier WITHOUT vmcnt drain: ds_writes drained (lgkmcnt), global
    // P-stores stay in flight across tiles.
    asm volatile("s_waitcnt lgkmcnt(0)" ::: "memory");
    __builtin_amdgcn_s_barrier();
    cur ^= 1;
  }

#pragma unroll
  for (int m = 0; m < 3; m++) {
    float s = ssum[m], q = ssq[m];
    s += __shfl_xor(s, 16); s += __shfl_xor(s, 32);
    q += __shfl_xor(q, 16); q += __shfl_xor(q, 32);
    if (kg == 0) {
      unsafeAtomicAdd(&stats[m * 256 + colb], s);
      unsafeAtomicAdd(&stats[m * 256 + 128 + colb], q);
    }
  }
}

// ---------------------------------------------------------------------------
// K_bn: 1 block.  Builds packed epilogue tables at swizzled index
// idx = m*128 + (c&7)*16 + (c>>3):
//   A4[idx] = {MT1[m,c], MT2[m,c], MT3[m,c], a}
//   B4[idx] = {MTq1[c], MTq2[c], MTq3[c], kv}   (q-parts zero for m != 1)
// a = gamma*rsqrt(var+eps); kv = beta - a*mu.
// ---------------------------------------------------------------------------
__global__ void k_bn(
    const float* __restrict__ stats,
    const float* __restrict__ gamma, const float* __restrict__ beta,
    const float* __restrict__ MT,
    float4* __restrict__ A4, float4* __restrict__ B4, float invN)
{
  int t = threadIdx.x;
  if (t < 384) {
    int m = t >> 7, c = t & 127;
    float mu = stats[m * 256 + c] * invN;
    float var = stats[m * 256 + 128 + c] * invN - mu * mu;
    float a = gamma[c] * rsqrtf(var + EPSBN);
    float kv = beta[c] - mu * a;
    int idx = m * 128 + (c & 7) * 16 + (c >> 3);
    A4[idx] = make_float4(MT[0 * 512 + m * 128 + c],
                          MT[1 * 512 + m * 128 + c],
                          MT[2 * 512 + m * 128 + c], a);
    if (m == 1)
      B4[idx] = make_float4(MT[0 * 512 + 384 + c],
                            MT[1 * 512 + 384 + c],
                            MT[2 * 512 + 384 + c], kv);
    else
      B4[idx] = make_float4(0.f, 0.f, 0.f, kv);
  }
}

// ---------------------------------------------------------------------------
// K1g: elementwise second-GEMM replacement.  16 lanes/row; per (row, m)
// one uint4 load = 8 bf16 cols; per (m, dword) conflict-free b128 LDS reads
// of the swizzled A4s/B4s tables; v = relu(a*P+kv); branchless q-accum.
// Also zeroes logit3R rows.  256-thr block: >256 LDS staging via strided
// loops (R17 lesson).
// ---------------------------------------------------------------------------
__global__ __launch_bounds__(256) void k1g_post(
    const unsigned short* __restrict__ Pb,
    const float4* __restrict__ A4, const float4* __restrict__ B4,
    float* __restrict__ slogA, float* __restrict__ qv,
    float* __restrict__ logit3R, int N, int N4, int nrt)
{
  __shared__ float4 A4s[384];
  __shared__ float4 B4s[384];
  const int tid = threadIdx.x;
  for (int i = tid; i < 384; i += 256) { A4s[i] = A4[i]; B4s[i] = B4[i]; }
  __syncthreads();

  const int l15 = tid & 15;
  const int rg  = tid >> 4;
  const size_t nf = (size_t)N * NFEAT;

  for (int it = blockIdx.x; it < nrt; it += gridDim.x) {
    // zero logit3R for these 16 rows x NREP reps (128 float4; tid<128)
    if (tid < 128) {
      int rep = tid >> 4;
      int zr = it * 16 + (tid & 15);
      if (zr < N)
        *(float4*)&logit3R[(size_t)rep * N4 + (size_t)zr * 4] =
            make_float4(0.f, 0.f, 0.f, 0.f);
    }

    int row = it * 16 + rg;
    if (row >= N) continue;

    float s0 = 0.f, s1 = 0.f, s2 = 0.f;
    float q0 = 0.f, q1 = 0.f, q2 = 0.f;
#pragma unroll
    for (int m = 0; m < 3; m++) {
      const uint4* p4 =
          (const uint4*)(Pb + (size_t)m * nf + (size_t)row * NFEAT + l15 * 8);
      uint4 u = p4[0];
      unsigned dw[4] = {u.x, u.y, u.z, u.w};
#pragma unroll
      for (int d = 0; d < 4; d++) {
        // cols c0+2d (lo ushort) and c0+2d+1 (hi ushort); c&7 = 2d / 2d+1
        {
          float4 ab = A4s[m * 128 + (2 * d) * 16 + l15];
          float4 bq = B4s[m * 128 + (2 * d) * 16 + l15];
          float P = bf2f((unsigned short)(dw[d] & 0xffffu));
          float v = fmaxf(fmaf(ab.w, P, bq.w), 0.f);
          s0 = fmaf(v, ab.x, s0); s1 = fmaf(v, ab.y, s1); s2 = fmaf(v, ab.z, s2);
          q0 = fmaf(v, bq.x, q0); q1 = fmaf(v, bq.y, q1); q2 = fmaf(v, bq.z, q2);
        }
        {
          float4 ab = A4s[m * 128 + (2 * d + 1) * 16 + l15];
          float4 bq = B4s[m * 128 + (2 * d + 1) * 16 + l15];
          float P = bf2f((unsigned short)(dw[d] >> 16));
          float v = fmaxf(fmaf(ab.w, P, bq.w), 0.f);
          s0 = fmaf(v, ab.x, s0); s1 = fmaf(v, ab.y, s1); s2 = fmaf(v, ab.z, s2);
          q0 = fmaf(v, bq.x, q0); q1 = fmaf(v, bq.y, q1); q2 = fmaf(v, bq.z, q2);
        }
      }
    }
#pragma unroll
    for (int off = 1; off < 16; off <<= 1) {
      s0 += __shfl_xor(s0, off); s1 += __shfl_xor(s1, off);
      s2 += __shfl_xor(s2, off);
      q0 += __shfl_xor(q0, off); q1 += __shfl_xor(q1, off);
      q2 += __shfl_xor(q2, off);
    }
    if (l15 == 0) {
      *(float4*)&slogA[(size_t)row * 4] = make_float4(s0, s1, s2, 0.f);
      *(float4*)&qv[(size_t)row * 4]    = make_float4(q0, q1, q2, 0.f);
    }
  }
}

// ---------------------------------------------------------------------------
// K_edge: 64 lanes = 21 edges x 3 comps; one atomic/lane, same-line merge,
// replica (waveID&7) spreads contention.
// ---------------------------------------------------------------------------
__global__ __launch_bounds__(256) void k_edge(
    const int* __restrict__ eidx, const float* __restrict__ ew,
    const float* __restrict__ q, float* __restrict__ logit3R,
    int E, int N4)
{
  const int wid  = (blockIdx.x * 256 + threadIdx.x) >> 6;
  const int lane = threadIdx.x & 63;
  const int el   = lane / 3;
  const int comp = lane - el * 3;
  if (el >= 21) return;
  const int e = wid * 21 + el;
  if (e >= E) return;

  int src = eidx[e];
  int dst = eidx[E + e];
  float w = ew[e];
  float qvv = q[(size_t)src * 4 + comp];
  int rep = wid & (NREP - 1);
  unsafeAtomicAdd(&logit3R[(size_t)rep * N4 + (size_t)dst * 4 + comp], qvv * w);
}

// ---------------------------------------------------------------------------
// K4t: out[r] = softmax(slog[r] + sum_rep logit3R[rep][r] + cb).
// ---------------------------------------------------------------------------
__global__ __launch_bounds__(256) void k4_final(
    const float* __restrict__ slogA, const float* __restrict__ logit3R,
    const float* __restrict__ cb,
    float* __restrict__ out, int N, int N4)
{
  int r = blockIdx.x * 256 + threadIdx.x;
  if (r >= N) return;
  float4 S = *(const float4*)&slogA[(size_t)r * 4];
  float l0 = S.x + cb[0], l1 = S.y + cb[1], l2 = S.z + cb[2];
#pragma unroll
  for (int rep = 0; rep < NREP; rep++) {
    float4 L = *(const float4*)&logit3R[(size_t)rep * N4 + (size_t)r * 4];
    l0 += L.x; l1 += L.y; l2 += L.z;
  }
  float mx = fmaxf(l0, fmaxf(l1, l2));
  float e0 = expf(l0 - mx), e1 = expf(l1 - mx), e2 = expf(l2 - mx);
  float inv = 1.f / (e0 + e1 + e2);
  out[(size_t)r * 3 + 0] = e0 * inv;
  out[(size_t)r * 3 + 1] = e1 * inv;
  out[(size_t)r * 3 + 2] = e2 * inv;
}

// ---------------------------------------------------------------------------
extern "C" void kernel_launch(void* const* d_in, const int* in_sizes, int n_in,
                              void* d_out, int out_size, void* d_ws, size_t ws_size,
                              hipStream_t stream)
{
  const float* feat  = (const float*)d_in[0];
  const int*   eidx  = (const int*)  d_in[1];
  const float* ew    = (const float*)d_in[2];
  const float* Ws    = (const float*)d_in[3];
  const float* bs    = (const float*)d_in[4];
  const float* Wi    = (const float*)d_in[5];
  const float* bi    = (const float*)d_in[6];
  const float* Wr    = (const float*)d_in[7];
  const float* br    = (const float*)d_in[8];
  const float* gamma = (const float*)d_in[9];
  const float* beta  = (const float*)d_in[10];
  const float* WtoI  = (const float*)d_in[11];
  const float* btoI  = (const float*)d_in[12];
  const float* WtoR  = (const float*)d_in[13];
  const float* btoR  = (const float*)d_in[14];
  const float* Wout  = (const float*)d_in[15];
  const float* bout  = (const float*)d_in[16];

  const int N = in_sizes[0] / NFEAT;
  const int E = in_sizes[2];
  const int N4 = 4 * N;
  const float invN = 1.0f / (float)N;
  float* out = (float*)d_out;

  float* logit3R = (float*)d_ws;                 // NREP*4*N
  float* slogA   = logit3R + (size_t)NREP * N4;  // 4*N
  float* qv      = slogA + 4 * (size_t)N;        // 4*N
  float* stats   = qv + 4 * (size_t)N;           // 768
  float* MT      = stats + 768;                  // 1536
  float* cb      = MT + 1536;                    // 4
  float4* A4     = (float4*)(cb + 4);            // 384 float4
  float4* B4     = A4 + 384;                     // 384 float4
  short* Whi     = (short*)(B4 + 384);           // 49152
  short* Wlo     = Whi + 49152;                  // 49152
  unsigned short* Pb = (unsigned short*)(Wlo + 49152);  // 3*N*128 bf16

  hipMemsetAsync(stats, 0, 768 * sizeof(float), stream);

  const int nt = (N + 63) / 64;           // 1563
  const int g1 = (nt + 2) / 3;            // 521
  const int nrt = (N + 15) / 16;          // 6250

  kp_params<<<30, 256, 0, stream>>>(Ws, Wi, Wr, WtoI, btoI, WtoR, btoR,
                                    Wout, bout, Whi, Wlo, MT, cb);
  k1a_store<<<g1, 512, 0, stream>>>(feat, Whi, Wlo, bs, bi, br, stats, Pb,
                                    N, nt);
  k_bn<<<1, 384, 0, stream>>>(stats, gamma, beta, MT, A4, B4, invN);
  k1g_post<<<2048, 256, 0, stream>>>(Pb, A4, B4, slogA, qv, logit3R,
                                     N, N4, nrt);
  const int nwaves = (E + 20) / 21;
  k_edge<<<(nwaves + 3) / 4, 256, 0, stream>>>(eidx, ew, qv, logit3R, E, N4);
  k4_final<<<(N + 255) / 256, 256, 0, stream>>>(slogA, logit3R, cb, out, N, N4);
}

// Round 21
// 126.868 us; speedup vs baseline: 2.1274x; 1.1654x over previous
//
#include <hip/hip_runtime.h>
#include <math.h>

#define NFEAT 128
#define EPSBN 1e-5f
#define LDA 136   // bf16 elems per LDS row: 128 + 8 pad
#define NREP 8    // logit3 replicas to spread atomic contention

typedef __attribute__((ext_vector_type(8))) short short8;
typedef __attribute__((ext_vector_type(4))) float f32x4;

__device__ __forceinline__ unsigned short f2bf(float x) {
  union { float f; unsigned u; } v; v.f = x;
  unsigned r = v.u + 0x7FFF + ((v.u >> 16) & 1);   // RNE
  return (unsigned short)(r >> 16);
}
__device__ __forceinline__ float bf2f(unsigned short h) {
  union { unsigned u; float f; } v; v.u = (unsigned)h << 16;
  return v.f;
}

// ---------------------------------------------------------------------------
// KP: blocks 0..23: W' = (W + I) as bf16 in MFMA B-fragment order (hi only —
// R20 measured absmax at the bf16 OUTPUT floor, so plain-bf16 GEMM precision
// suffices; threshold 2e-2).  Blocks 24..29: fold back-half into MT + cb.
//   logits = S@M1 + I@M3 + R@M4 + NB@M2 + cb
// MT layout: MT[cl*512 + part*128 + k], part: 0=S 1=I 2=R 3=NB.
// ---------------------------------------------------------------------------
__global__ __launch_bounds__(256) void kp_params(
    const float* __restrict__ Ws, const float* __restrict__ Wi,
    const float* __restrict__ Wr,
    const float* __restrict__ WtoI, const float* __restrict__ btoI,
    const float* __restrict__ WtoR, const float* __restrict__ btoR,
    const float* __restrict__ Wout, const float* __restrict__ bout,
    short* __restrict__ Whi,
    float* __restrict__ MT, float* __restrict__ cb)
{
  const int tid = threadIdx.x;
  if (blockIdx.x < 24) {
    int t = blockIdx.x * 256 + tid;   // 6144 total
    int m   = t >> 11;
    int rem = t & 2047;
    int kf  = rem >> 9;
    int kg  = (rem >> 7) & 3;
    int c   = rem & 127;
    const float* W = (m == 0) ? Ws : ((m == 1) ? Wi : Wr);
    short hb[8];
#pragma unroll
    for (int j = 0; j < 8; j++) {
      int k = kf * 32 + kg * 8 + j;
      float w = W[(size_t)k * NFEAT + c] + (k == c ? 1.0f : 0.0f);
      hb[j] = (short)f2bf(w);
    }
    int base = ((m * 16 + kf * 4 + kg) << 10) + (c << 3);
    *(short8*)&Whi[base] = *(short8*)hb;
    return;
  }

  int t = (blockIdx.x - 24) * 256 + tid;   // 0..1535
  int cl = t / 512;
  int idx = t - cl * 512;
  int part = idx >> 7, k = idx & 127;
  float val;
  if (part == 0) {            // S: Wo1 + WtoI_top @ (Wo2-Wo1)
    float s = Wout[k * 3 + cl];
    for (int f = 0; f < 128; f++)
      s = fmaf(WtoI[k * 128 + f],
               Wout[(128 + f) * 3 + cl] - Wout[f * 3 + cl], s);
    val = s;
  } else if (part == 1) {     // I: Wo2 + WtoR @ (Wo3-Wo2)
    float s = Wout[(128 + k) * 3 + cl];
    for (int f = 0; f < 128; f++)
      s = fmaf(WtoR[k * 128 + f],
               Wout[(256 + f) * 3 + cl] - Wout[(128 + f) * 3 + cl], s);
    val = s;
  } else if (part == 2) {     // R: Wo3
    val = Wout[(256 + k) * 3 + cl];
  } else {                    // NB: WtoI_bot @ (Wo2-Wo1)
    float s = 0.f;
    for (int f = 0; f < 128; f++)
      s = fmaf(WtoI[(128 + k) * 128 + f],
               Wout[(128 + f) * 3 + cl] - Wout[f * 3 + cl], s);
    val = s;
  }
  MT[cl * 512 + idx] = val;

  if (blockIdx.x == 24 && tid < 3) {
    float s = bout[tid];
    for (int f = 0; f < 128; f++) {
      s = fmaf(btoI[f], Wout[(128 + f) * 3 + tid] - Wout[f * 3 + tid], s);
      s = fmaf(btoR[f], Wout[(256 + f) * 3 + tid] - Wout[(128 + f) * 3 + tid], s);
    }
    cb[tid] = s;
  }
}

// ---------------------------------------------------------------------------
// K1a_store: plain-bf16 GEMM P_w = feat @ (W_w+I) + b_w.  fp32 column
// sum/sumsq stats from the accumulators; P stored as single bf16.
// Single MFMA per product (was 3 with split-bf16); LDS dbuf 2x17.4 KB.
// Loop barrier is raw s_barrier + lgkmcnt(0) — no vmcnt drain, P-stores
// stay in flight across tiles.
// ---------------------------------------------------------------------------
__global__ __launch_bounds__(512, 2) void k1a_store(
    const float* __restrict__ feat,
    const short* __restrict__ Whi,
    const float* __restrict__ bs, const float* __restrict__ bi,
    const float* __restrict__ br,
    float* __restrict__ stats,           // 6*128
    unsigned short* __restrict__ Pb,     // 3*N*128 bf16
    int N, int ntiles)
{
  __shared__ short Ah[2][64 * LDA];

  const int tid  = threadIdx.x;
  const int lane = tid & 63;
  const int wv   = tid >> 6;
  const int colb = wv * 16 + (lane & 15);
  const int kg   = lane >> 4;
  const int krow = kg * 8;

  const int sr = tid >> 3;
  const int so = tid & 7;

  const float bias[3] = {bs[colb], bi[colb], br[colb]};
  float ssum[3] = {0.f, 0.f, 0.f}, ssq[3] = {0.f, 0.f, 0.f};
  const size_t nf = (size_t)N * NFEAT;

  float4 pf[4];
  {
    int gr = blockIdx.x * 64 + sr; if (gr >= N) gr = N - 1;
    const float4* s4 = (const float4*)(feat + (size_t)gr * NFEAT + so * 16);
#pragma unroll
    for (int q = 0; q < 4; q++) pf[q] = s4[q];
    short hbuf[16];
#pragma unroll
    for (int q = 0; q < 4; q++) {
      float xs[4] = {pf[q].x, pf[q].y, pf[q].z, pf[q].w};
#pragma unroll
      for (int cc = 0; cc < 4; cc++) hbuf[q * 4 + cc] = (short)f2bf(xs[cc]);
    }
    *(short8*)&Ah[0][sr * LDA + so * 16]     = *(short8*)(hbuf);
    *(short8*)&Ah[0][sr * LDA + so * 16 + 8] = *(short8*)(hbuf + 8);
  }
  __syncthreads();

  int cur = 0;
  for (int tile = blockIdx.x; tile < ntiles; tile += gridDim.x) {
    const int row0 = tile * 64;
    const int ntile = tile + gridDim.x;
    const bool have_next = ntile < ntiles;

    if (have_next) {
      int gr = ntile * 64 + sr; if (gr >= N) gr = N - 1;
      const float4* s4 = (const float4*)(feat + (size_t)gr * NFEAT + so * 16);
#pragma unroll
      for (int q = 0; q < 4; q++) pf[q] = s4[q];
    }

    const short* ah_c = &Ah[cur][0];

    f32x4 acc[3][4];
#pragma unroll
    for (int m = 0; m < 3; m++)
#pragma unroll
      for (int rf = 0; rf < 4; rf++)
        acc[m][rf] = (f32x4){0.f, 0.f, 0.f, 0.f};

#pragma unroll
    for (int kf = 0; kf < 4; kf++) {
      short8 bh[3];
#pragma unroll
      for (int m = 0; m < 3; m++) {
        int fb = ((m * 16 + kf * 4 + kg) << 10) + (colb << 3);
        bh[m] = *(const short8*)&Whi[fb];
      }
      short8 ah[4];
#pragma unroll
      for (int rf = 0; rf < 4; rf++) {
        int off = (rf * 16 + (lane & 15)) * LDA + kf * 32 + krow;
        ah[rf] = *(const short8*)&ah_c[off];
      }
#pragma unroll
      for (int m = 0; m < 3; m++) {
#pragma unroll
        for (int rf = 0; rf < 4; rf++) {
          acc[m][rf] = __builtin_amdgcn_mfma_f32_16x16x32_bf16(
              ah[rf], bh[m], acc[m][rf], 0, 0, 0);
        }
      }
    }

    // epilogue: fp32 stats + single-bf16 P store (fire-and-forget)
#pragma unroll
    for (int rf = 0; rf < 4; rf++) {
      int lrb = rf * 16 + kg * 4;
#pragma unroll
      for (int g = 0; g < 4; g++) {
        int gr = row0 + lrb + g;
        bool ok = gr < N;
#pragma unroll
        for (int m = 0; m < 3; m++) {
          float v = acc[m][rf][g] + bias[m];
          if (ok) {
            ssum[m] += v;
            ssq[m]  += v * v;
            Pb[(size_t)m * nf + (size_t)gr * NFEAT + colb] = f2bf(v);
          }
        }
      }
    }

    if (have_next) {
      short hbuf[16];
#pragma unroll
      for (int q = 0; q < 4; q++) {
        float xs[4] = {pf[q].x, pf[q].y, pf[q].z, pf[q].w};
#pragma unroll
        for (int cc = 0; cc < 4; cc++) hbuf[q * 4 + cc] = (short)f2bf(xs[cc]);
      }
      int nb = cur ^ 1;
      *(short8*)&Ah[nb][sr * LDA + so * 16]     = *(short8*)(hbuf);
      *(short8*)&Ah[nb][sr * LDA + so * 16 + 8] = *(short8*)(hbuf + 8);
    }
    // barrier WITHOUT vmcnt drain
    asm volatile("s_waitcnt lgkmcnt(0)" ::: "memory");
    __builtin_amdgcn_s_barrier();
    cur ^= 1;
  }

#pragma unroll
  for (int m = 0; m < 3; m++) {
    float s = ssum[m], q = ssq[m];
    s += __shfl_xor(s, 16); s += __shfl_xor(s, 32);
    q += __shfl_xor(q, 16); q += __shfl_xor(q, 32);
    if (kg == 0) {
      unsafeAtomicAdd(&stats[m * 256 + colb], s);
      unsafeAtomicAdd(&stats[m * 256 + 128 + colb], q);
    }
  }
}

// ---------------------------------------------------------------------------
// K_bn: 1 block.  Builds packed epilogue tables at swizzled index
// idx = m*128 + (c&7)*16 + (c>>3):
//   A4[idx] = {MT1[m,c], MT2[m,c], MT3[m,c], a}
//   B4[idx] = {MTq1[c], MTq2[c], MTq3[c], kv}   (q-parts zero for m != 1)
// a = gamma*rsqrt(var+eps); kv = beta - a*mu.
// ---------------------------------------------------------------------------
__global__ void k_bn(
    const float* __restrict__ stats,
    const float* __restrict__ gamma, const float* __restrict__ beta,
    const float* __restrict__ MT,
    float4* __restrict__ A4, float4* __restrict__ B4, float invN)
{
  int t = threadIdx.x;
  if (t < 384) {
    int m = t >> 7, c = t & 127;
    float mu = stats[m * 256 + c] * invN;
    float var = stats[m * 256 + 128 + c] * invN - mu * mu;
    float a = gamma[c] * rsqrtf(var + EPSBN);
    float kv = beta[c] - mu * a;
    int idx = m * 128 + (c & 7) * 16 + (c >> 3);
    A4[idx] = make_float4(MT[0 * 512 + m * 128 + c],
                          MT[1 * 512 + m * 128 + c],
                          MT[2 * 512 + m * 128 + c], a);
    if (m == 1)
      B4[idx] = make_float4(MT[0 * 512 + 384 + c],
                            MT[1 * 512 + 384 + c],
                            MT[2 * 512 + 384 + c], kv);
    else
      B4[idx] = make_float4(0.f, 0.f, 0.f, kv);
  }
}

// ---------------------------------------------------------------------------
// K1g: elementwise second-GEMM replacement.  16 lanes/row; per (row, m)
// one uint4 load = 8 bf16 cols; per (m, dword) conflict-free b128 LDS reads
// of the swizzled A4s/B4s tables; v = relu(a*P+kv); branchless q-accum.
// Also zeroes logit3R rows.  256-thr block: >256 LDS staging via strided
// loops (R17 lesson).
// ---------------------------------------------------------------------------
__global__ __launch_bounds__(256) void k1g_post(
    const unsigned short* __restrict__ Pb,
    const float4* __restrict__ A4, const float4* __restrict__ B4,
    float* __restrict__ slogA, float* __restrict__ qv,
    float* __restrict__ logit3R, int N, int N4, int nrt)
{
  __shared__ float4 A4s[384];
  __shared__ float4 B4s[384];
  const int tid = threadIdx.x;
  for (int i = tid; i < 384; i += 256) { A4s[i] = A4[i]; B4s[i] = B4[i]; }
  __syncthreads();

  const int l15 = tid & 15;
  const int rg  = tid >> 4;
  const size_t nf = (size_t)N * NFEAT;

  for (int it = blockIdx.x; it < nrt; it += gridDim.x) {
    // zero logit3R for these 16 rows x NREP reps (128 float4; tid<128)
    if (tid < 128) {
      int rep = tid >> 4;
      int zr = it * 16 + (tid & 15);
      if (zr < N)
        *(float4*)&logit3R[(size_t)rep * N4 + (size_t)zr * 4] =
            make_float4(0.f, 0.f, 0.f, 0.f);
    }

    int row = it * 16 + rg;
    if (row >= N) continue;

    float s0 = 0.f, s1 = 0.f, s2 = 0.f;
    float q0 = 0.f, q1 = 0.f, q2 = 0.f;
#pragma unroll
    for (int m = 0; m < 3; m++) {
      const uint4* p4 =
          (const uint4*)(Pb + (size_t)m * nf + (size_t)row * NFEAT + l15 * 8);
      uint4 u = p4[0];
      unsigned dw[4] = {u.x, u.y, u.z, u.w};
#pragma unroll
      for (int d = 0; d < 4; d++) {
        {
          float4 ab = A4s[m * 128 + (2 * d) * 16 + l15];
          float4 bq = B4s[m * 128 + (2 * d) * 16 + l15];
          float P = bf2f((unsigned short)(dw[d] & 0xffffu));
          float v = fmaxf(fmaf(ab.w, P, bq.w), 0.f);
          s0 = fmaf(v, ab.x, s0); s1 = fmaf(v, ab.y, s1); s2 = fmaf(v, ab.z, s2);
          q0 = fmaf(v, bq.x, q0); q1 = fmaf(v, bq.y, q1); q2 = fmaf(v, bq.z, q2);
        }
        {
          float4 ab = A4s[m * 128 + (2 * d + 1) * 16 + l15];
          float4 bq = B4s[m * 128 + (2 * d + 1) * 16 + l15];
          float P = bf2f((unsigned short)(dw[d] >> 16));
          float v = fmaxf(fmaf(ab.w, P, bq.w), 0.f);
          s0 = fmaf(v, ab.x, s0); s1 = fmaf(v, ab.y, s1); s2 = fmaf(v, ab.z, s2);
          q0 = fmaf(v, bq.x, q0); q1 = fmaf(v, bq.y, q1); q2 = fmaf(v, bq.z, q2);
        }
      }
    }
#pragma unroll
    for (int off = 1; off < 16; off <<= 1) {
      s0 += __shfl_xor(s0, off); s1 += __shfl_xor(s1, off);
      s2 += __shfl_xor(s2, off);
      q0 += __shfl_xor(q0, off); q1 += __shfl_xor(q1, off);
      q2 += __shfl_xor(q2, off);
    }
    if (l15 == 0) {
      *(float4*)&slogA[(size_t)row * 4] = make_float4(s0, s1, s2, 0.f);
      *(float4*)&qv[(size_t)row * 4]    = make_float4(q0, q1, q2, 0.f);
    }
  }
}

// ---------------------------------------------------------------------------
// K_edge: 64 lanes = 21 edges x 3 comps; one atomic/lane, same-line merge,
// replica (waveID&7) spreads contention.
// ---------------------------------------------------------------------------
__global__ __launch_bounds__(256) void k_edge(
    const int* __restrict__ eidx, const float* __restrict__ ew,
    const float* __restrict__ q, float* __restrict__ logit3R,
    int E, int N4)
{
  const int wid  = (blockIdx.x * 256 + threadIdx.x) >> 6;
  const int lane = threadIdx.x & 63;
  const int el   = lane / 3;
  const int comp = lane - el * 3;
  if (el >= 21) return;
  const int e = wid * 21 + el;
  if (e >= E) return;

  int src = eidx[e];
  int dst = eidx[E + e];
  float w = ew[e];
  float qvv = q[(size_t)src * 4 + comp];
  int rep = wid & (NREP - 1);
  unsafeAtomicAdd(&logit3R[(size_t)rep * N4 + (size_t)dst * 4 + comp], qvv * w);
}

// ---------------------------------------------------------------------------
// K4t: out[r] = softmax(slog[r] + sum_rep logit3R[rep][r] + cb).
// ---------------------------------------------------------------------------
__global__ __launch_bounds__(256) void k4_final(
    const float* __restrict__ slogA, const float* __restrict__ logit3R,
    const float* __restrict__ cb,
    float* __restrict__ out, int N, int N4)
{
  int r = blockIdx.x * 256 + threadIdx.x;
  if (r >= N) return;
  float4 S = *(const float4*)&slogA[(size_t)r * 4];
  float l0 = S.x + cb[0], l1 = S.y + cb[1], l2 = S.z + cb[2];
#pragma unroll
  for (int rep = 0; rep < NREP; rep++) {
    float4 L = *(const float4*)&logit3R[(size_t)rep * N4 + (size_t)r * 4];
    l0 += L.x; l1 += L.y; l2 += L.z;
  }
  float mx = fmaxf(l0, fmaxf(l1, l2));
  float e0 = expf(l0 - mx), e1 = expf(l1 - mx), e2 = expf(l2 - mx);
  float inv = 1.f / (e0 + e1 + e2);
  out[(size_t)r * 3 + 0] = e0 * inv;
  out[(size_t)r * 3 + 1] = e1 * inv;
  out[(size_t)r * 3 + 2] = e2 * inv;
}

// ---------------------------------------------------------------------------
extern "C" void kernel_launch(void* const* d_in, const int* in_sizes, int n_in,
                              void* d_out, int out_size, void* d_ws, size_t ws_size,
                              hipStream_t stream)
{
  const float* feat  = (const float*)d_in[0];
  const int*   eidx  = (const int*)  d_in[1];
  const float* ew    = (const float*)d_in[2];
  const float* Ws    = (const float*)d_in[3];
  const float* bs    = (const float*)d_in[4];
  const float* Wi    = (const float*)d_in[5];
  const float* bi    = (const float*)d_in[6];
  const float* Wr    = (const float*)d_in[7];
  const float* br    = (const float*)d_in[8];
  const float* gamma = (const float*)d_in[9];
  const float* beta  = (const float*)d_in[10];
  const float* WtoI  = (const float*)d_in[11];
  const float* btoI  = (const float*)d_in[12];
  const float* WtoR  = (const float*)d_in[13];
  const float* btoR  = (const float*)d_in[14];
  const float* Wout  = (const float*)d_in[15];
  const float* bout  = (const float*)d_in[16];

  const int N = in_sizes[0] / NFEAT;
  const int E = in_sizes[2];
  const int N4 = 4 * N;
  const float invN = 1.0f / (float)N;
  float* out = (float*)d_out;

  float* logit3R = (float*)d_ws;                 // NREP*4*N
  float* slogA   = logit3R + (size_t)NREP * N4;  // 4*N
  float* qv      = slogA + 4 * (size_t)N;        // 4*N
  float* stats   = qv + 4 * (size_t)N;           // 768
  float* MT      = stats + 768;                  // 1536
  float* cb      = MT + 1536;                    // 4
  float4* A4     = (float4*)(cb + 4);            // 384 float4
  float4* B4     = A4 + 384;                     // 384 float4
  short* Whi     = (short*)(B4 + 384);           // 49152
  unsigned short* Pb = (unsigned short*)(Whi + 49152);  // 3*N*128 bf16

  hipMemsetAsync(stats, 0, 768 * sizeof(float), stream);

  const int nt = (N + 63) / 64;           // 1563
  const int g1 = (nt + 2) / 3;            // 521
  const int nrt = (N + 15) / 16;          // 6250

  kp_params<<<30, 256, 0, stream>>>(Ws, Wi, Wr, WtoI, btoI, WtoR, btoR,
                                    Wout, bout, Whi, MT, cb);
  k1a_store<<<g1, 512, 0, stream>>>(feat, Whi, bs, bi, br, stats, Pb, N, nt);
  k_bn<<<1, 384, 0, stream>>>(stats, gamma, beta, MT, A4, B4, invN);
  k1g_post<<<2048, 256, 0, stream>>>(Pb, A4, B4, slogA, qv, logit3R,
                                     N, N4, nrt);
  const int nwaves = (E + 20) / 21;
  k_edge<<<(nwaves + 3) / 4, 256, 0, stream>>>(eidx, ew, qv, logit3R, E, N4);
  k4_final<<<(N + 255) / 256, 256, 0, stream>>>(slogA, logit3R, cb, out, N, N4);
}